// Round 2
// baseline (3328.848 us; speedup 1.0000x reference)
//
#include <hip/hip_runtime.h>
#include <hip/hip_bf16.h>
#include <math.h>

using bf16 = __hip_bfloat16;
typedef const float* __restrict__ cfp;

static constexpr int kS = 1024, kE = 128, kH = 8, kDH = 16, kDFF = 512;
static constexpr float kEps = 1e-5f;

__device__ __forceinline__ float geluf(float x) { return 0.5f * x * (1.f + erff(x * 0.70710678118654752f)); }

// ---------------- dtype detection ----------------
// If d_in really holds f32, its low half-words reinterpreted as bf16 have
// uniformly-random exponent bits -> values >= 2^54 occur w.p. ~30% per elem.
// Real bf16 N(0,1) data never exceeds ~10. flag=1 => inputs are f32.
__global__ void detect_kernel(const unsigned short* __restrict__ xb, int n, int* __restrict__ flag) {
  int i = blockIdx.x * 256 + threadIdx.x;
  if (i >= n) return;
  unsigned short u = xb[i];
  int e = (u >> 7) & 0xFF;
  if (e >= 0xB5) *flag = 1;
}

struct CvtArgs { const void* p[27]; int cum[28]; };

__global__ void convert_kernel(CvtArgs a, const int* __restrict__ flag,
                               float* __restrict__ out, int total) {
  int idx = blockIdx.x * 256 + threadIdx.x;
  if (idx >= total) return;
  int id = 0;
  while (idx >= a.cum[id + 1]) ++id;
  int local = idx - a.cum[id];
  float v;
  if (*flag) v = ((const float*)a.p[id])[local];
  else       v = __bfloat162float(((const bf16*)a.p[id])[local]);
  out[idx] = v;
}

// ---------------- fused conv1+bn1+gelu+conv2+bn2+gelu -> xsrc [B*S, E] ----------------
// GEMM view: A[(b,s), kg] with kg = c1*4 + r built on the fly; B[kg, e] = w2[e*2048+kg].
__global__ __launch_bounds__(256) void conv_kernel(
    cfp x, cfp w1, cfp c1b, cfp g1, cfp b1, cfp m1, cfp v1,
    cfp w2, cfp c2b, cfp g2, cfp b2, cfp m2, cfp v2,
    float* __restrict__ xsrc) {
  __shared__ float xs[4][72];      // halo tile: s0-3 .. s0+68
  __shared__ float As[64][65];     // [k][m]
  __shared__ float Bs[64][129];    // [k][n]
  int tid = threadIdx.x;
  int bb = blockIdx.x >> 4, s0 = (blockIdx.x & 15) << 6;

  for (int i = tid; i < 288; i += 256) {
    int t = i >> 2, r = i & 3;
    int gs = s0 - 3 + t;
    xs[r][t] = (gs >= 0 && gs < kS) ? x[(gs + bb * kS) * 4 + r] : 0.f;
  }

  float acc[4][8];
#pragma unroll
  for (int i = 0; i < 4; ++i)
#pragma unroll
    for (int j = 0; j < 8; ++j) acc[i][j] = 0.f;

  int ri = tid >> 4, ci = tid & 15;
  int m = tid & 63, kbase = tid >> 6;

  for (int k0 = 0; k0 < 2048; k0 += 64) {
    __syncthreads();
    for (int i = tid; i < 8192; i += 256) {
      int n = i >> 6, k = i & 63;
      Bs[k][n] = w2[n * 2048 + k0 + k];
    }
#pragma unroll
    for (int j = 0; j < 16; ++j) {
      int k = kbase + 4 * j;
      int kg = k0 + k;
      int c1 = kg >> 2, r = kg & 3;
      float h = c1b[c1];
#pragma unroll
      for (int t = 0; t < 8; ++t) h += xs[r][m + t] * w1[c1 * 8 + t];
      float hn = (h - m1[c1]) * (g1[c1] * __frsqrt_rn(v1[c1] + kEps)) + b1[c1];
      As[k][m] = geluf(hn);
    }
    __syncthreads();
    for (int k = 0; k < 64; ++k) {
      float a0 = As[k][ri * 4 + 0], a1 = As[k][ri * 4 + 1];
      float a2 = As[k][ri * 4 + 2], a3 = As[k][ri * 4 + 3];
#pragma unroll
      for (int j = 0; j < 8; ++j) {
        float bv = Bs[k][ci * 8 + j];
        acc[0][j] += a0 * bv; acc[1][j] += a1 * bv;
        acc[2][j] += a2 * bv; acc[3][j] += a3 * bv;
      }
    }
  }
#pragma unroll
  for (int j = 0; j < 8; ++j) {
    int n = ci * 8 + j;
    float sc = g2[n] / sqrtf(v2[n] + kEps);
    float bias = c2b[n], mu = m2[n], bt = b2[n];
#pragma unroll
    for (int i = 0; i < 4; ++i) {
      float val = acc[i][j] + bias;
      val = (val - mu) * sc + bt;
      xsrc[(size_t)(bb * kS + s0 + ri * 4 + i) * kE + n] = geluf(val);
    }
  }
}

// ---------------- QKV projection (PE computed inline) ----------------
__global__ __launch_bounds__(256) void qkv_kernel(
    cfp xsrc, cfp wq, cfp wk, cfp wv,
    float* __restrict__ q, float* __restrict__ k, float* __restrict__ v) {
  __shared__ float Xst[128][65];   // [k][m]
  __shared__ float Wst[32][129];   // [k][n]
  int tid = threadIdx.x;
  int row0 = blockIdx.x << 6;
  int s0 = row0 & (kS - 1);
  int bb = row0 >> 10;
  cfp W = (blockIdx.y == 0) ? wq : (blockIdx.y == 1) ? wk : wv;
  float* out = (blockIdx.y == 0) ? q : (blockIdx.y == 1) ? k : v;

  for (int i = tid; i < 8192; i += 256) {
    int mm = i >> 7, kk = i & 127;
    int srow = s0 + mm;
    int i2 = kk >> 1;
    float div = expf((float)i2 * (-0.14391156824963732f));   // exp(-2i*ln(1e4)/128)
    float ang = (float)srow * div * 0.125f;                  // * (E/S)
    float pev = (kk & 1) ? cosf(ang) : sinf(ang);
    Xst[kk][mm] = xsrc[(size_t)(row0 + mm) * kE + kk] + pev;
  }

  float acc[4][8];
#pragma unroll
  for (int i = 0; i < 4; ++i)
#pragma unroll
    for (int j = 0; j < 8; ++j) acc[i][j] = 0.f;
  int ri = tid >> 4, ci = tid & 15;

  for (int k0 = 0; k0 < 128; k0 += 32) {
    __syncthreads();
    for (int i = tid; i < 4096; i += 256) {
      int n = i >> 5, kk = i & 31;
      Wst[kk][n] = W[n * kE + k0 + kk];
    }
    __syncthreads();
    for (int kk = 0; kk < 32; ++kk) {
      int kg = k0 + kk;
      float a0 = Xst[kg][ri * 4 + 0], a1 = Xst[kg][ri * 4 + 1];
      float a2 = Xst[kg][ri * 4 + 2], a3 = Xst[kg][ri * 4 + 3];
#pragma unroll
      for (int j = 0; j < 8; ++j) {
        float bv = Wst[kk][ci * 8 + j];
        acc[0][j] += a0 * bv; acc[1][j] += a1 * bv;
        acc[2][j] += a2 * bv; acc[3][j] += a3 * bv;
      }
    }
  }
#pragma unroll
  for (int i = 0; i < 4; ++i) {
    int srow = s0 + ri * 4 + i;
#pragma unroll
    for (int j = 0; j < 8; ++j) {
      int n = ci * 8 + j;
      out[((size_t)(bb * kH + (n >> 4)) * kS + srow) * kDH + (n & 15)] = acc[i][j];
    }
  }
}

// ---------------- attention (flash-style, post-softmax rel bias as 2nd accumulator) ----------------
__global__ __launch_bounds__(256) void attn_kernel(
    cfp q, cfp k, cfp v, cfp relb, float* __restrict__ o) {
  __shared__ float rb[2048];
  int tid = threadIdx.x;
  int qt = blockIdx.x, h = blockIdx.y, bb = blockIdx.z;
  for (int t = tid; t < 2047; t += 256) rb[t] = relb[t * kH + h];
  __syncthreads();
  int i = qt * 256 + tid;
  cfp qrow = q + ((size_t)(bb * kH + h) * kS + i) * kDH;
  cfp K = k + (size_t)(bb * kH + h) * kS * kDH;
  cfp V = v + (size_t)(bb * kH + h) * kS * kDH;
  float qr[16];
#pragma unroll
  for (int d = 0; d < 16; ++d) qr[d] = qrow[d];
  const float scale = 0.088388347648318447f;   // 128^-0.5

  float mx = -1e30f;
  for (int j = 0; j < kS; ++j) {
    cfp kj = K + j * 16;
    float s = 0.f;
#pragma unroll
    for (int d = 0; d < 16; ++d) s += qr[d] * kj[d];
    mx = fmaxf(mx, s * scale);
  }
  float l = 0.f, accv[16], accb[16];
#pragma unroll
  for (int d = 0; d < 16; ++d) { accv[d] = 0.f; accb[d] = 0.f; }
  for (int j = 0; j < kS; ++j) {
    cfp kj = K + j * 16;
    cfp vj = V + j * 16;
    float s = 0.f;
#pragma unroll
    for (int d = 0; d < 16; ++d) s += qr[d] * kj[d];
    float e = expf(s * scale - mx);
    l += e;
    float wb = rb[i - j + 1023];
#pragma unroll
    for (int d = 0; d < 16; ++d) {
      float vv = vj[d];
      accv[d] += e * vv;
      accb[d] += wb * vv;
    }
  }
  float inv = 1.f / l;
  float* orow = o + (size_t)(bb * kS + i) * kE + h * kDH;
#pragma unroll
  for (int d = 0; d < 16; ++d) orow[d] = accv[d] * inv + accb[d];
}

// ---------------- LN(attn out) + residual + LN1 -> att ----------------
__global__ __launch_bounds__(256) void ln_kernel(
    cfp o, cfp xsrc, cfp lag, cfp lab, cfp l1g, cfp l1b, float* __restrict__ att) {
  int row = blockIdx.x * 4 + (threadIdx.x >> 6);
  int lane = threadIdx.x & 63;
  const float2* orow = (const float2*)(o + (size_t)row * kE);
  float2 a = orow[lane];
  float sum = a.x + a.y;
  for (int off = 1; off < 64; off <<= 1) sum += __shfl_xor(sum, off);
  float mean = sum * (1.f / 128.f);
  float d0 = a.x - mean, d1 = a.y - mean;
  float ss = d0 * d0 + d1 * d1;
  for (int off = 1; off < 64; off <<= 1) ss += __shfl_xor(ss, off);
  float inv = 1.f / sqrtf(ss * (1.f / 128.f) + kEps);
  float t0 = d0 * inv * lag[2 * lane]     + lab[2 * lane];
  float t1 = d1 * inv * lag[2 * lane + 1] + lab[2 * lane + 1];
  const float2* xrow = (const float2*)(xsrc + (size_t)row * kE);
  float2 xv = xrow[lane];
  t0 += xv.x; t1 += xv.y;
  float sum2 = t0 + t1;
  for (int off = 1; off < 64; off <<= 1) sum2 += __shfl_xor(sum2, off);
  float mean2 = sum2 * (1.f / 128.f);
  float e0 = t0 - mean2, e1 = t1 - mean2;
  float ss2 = e0 * e0 + e1 * e1;
  for (int off = 1; off < 64; off <<= 1) ss2 += __shfl_xor(ss2, off);
  float inv2 = 1.f / sqrtf(ss2 * (1.f / 128.f) + kEps);
  float r0 = e0 * inv2 * l1g[2 * lane]     + l1b[2 * lane];
  float r1 = e1 * inv2 * l1g[2 * lane + 1] + l1b[2 * lane + 1];
  ((float2*)(att + (size_t)row * kE))[lane] = make_float2(r0, r1);
}

// ---------------- FF1: att @ w1^T + b1, relu ----------------
__global__ __launch_bounds__(256) void ff1_kernel(
    cfp att, cfp w1, cfp fb1, float* __restrict__ ff1) {
  __shared__ float Xst[128][65];
  __shared__ float Wst[32][129];
  int tid = threadIdx.x;
  int row0 = blockIdx.x << 6;
  int n0 = blockIdx.y << 7;

  for (int i = tid; i < 8192; i += 256) {
    int mm = i >> 7, kk = i & 127;
    Xst[kk][mm] = att[(size_t)(row0 + mm) * kE + kk];
  }
  float acc[4][8];
#pragma unroll
  for (int i = 0; i < 4; ++i)
#pragma unroll
    for (int j = 0; j < 8; ++j) acc[i][j] = 0.f;
  int ri = tid >> 4, ci = tid & 15;

  for (int k0 = 0; k0 < 128; k0 += 32) {
    __syncthreads();
    for (int i = tid; i < 4096; i += 256) {
      int n = i >> 5, kk = i & 31;
      Wst[kk][n] = w1[(n0 + n) * kE + k0 + kk];
    }
    __syncthreads();
    for (int kk = 0; kk < 32; ++kk) {
      int kg = k0 + kk;
      float a0 = Xst[kg][ri * 4 + 0], a1 = Xst[kg][ri * 4 + 1];
      float a2 = Xst[kg][ri * 4 + 2], a3 = Xst[kg][ri * 4 + 3];
#pragma unroll
      for (int j = 0; j < 8; ++j) {
        float bv = Wst[kk][ci * 8 + j];
        acc[0][j] += a0 * bv; acc[1][j] += a1 * bv;
        acc[2][j] += a2 * bv; acc[3][j] += a3 * bv;
      }
    }
  }
#pragma unroll
  for (int i = 0; i < 4; ++i)
#pragma unroll
    for (int j = 0; j < 8; ++j) {
      int n = ci * 8 + j;
      float val = acc[i][j] + fb1[n0 + n];
      ff1[(size_t)(row0 + ri * 4 + i) * kDFF + n0 + n] = fmaxf(val, 0.f);
    }
}

// ---------------- FF2 + bias + residual + LN2 + GAP partial ----------------
__global__ __launch_bounds__(256) void ff2_kernel(
    cfp ff1v, cfp att, cfp w2, cfp fb2, cfp l2g, cfp l2b, float* __restrict__ outacc) {
  __shared__ float Xst[64][65];
  __shared__ float Wst[64][129];
  __shared__ float red[128];
  int tid = threadIdx.x;
  int row0 = blockIdx.x << 6;
  int bb = row0 >> 10;
  if (tid < 128) red[tid] = 0.f;

  float acc[4][8];
#pragma unroll
  for (int i = 0; i < 4; ++i)
#pragma unroll
    for (int j = 0; j < 8; ++j) acc[i][j] = 0.f;
  int ri = tid >> 4, ci = tid & 15;

  for (int k0 = 0; k0 < 512; k0 += 64) {
    __syncthreads();
    for (int i = tid; i < 4096; i += 256) {
      int mm = i >> 6, kk = i & 63;
      Xst[kk][mm] = ff1v[(size_t)(row0 + mm) * kDFF + k0 + kk];
    }
    for (int i = tid; i < 8192; i += 256) {
      int n = i >> 6, kk = i & 63;
      Wst[kk][n] = w2[n * kDFF + k0 + kk];
    }
    __syncthreads();
    for (int kk = 0; kk < 64; ++kk) {
      float a0 = Xst[kk][ri * 4 + 0], a1 = Xst[kk][ri * 4 + 1];
      float a2 = Xst[kk][ri * 4 + 2], a3 = Xst[kk][ri * 4 + 3];
#pragma unroll
      for (int j = 0; j < 8; ++j) {
        float bv = Wst[kk][ci * 8 + j];
        acc[0][j] += a0 * bv; acc[1][j] += a1 * bv;
        acc[2][j] += a2 * bv; acc[3][j] += a3 * bv;
      }
    }
  }

  float colsum[8];
#pragma unroll
  for (int j = 0; j < 8; ++j) colsum[j] = 0.f;
#pragma unroll
  for (int i = 0; i < 4; ++i) {
    int row = row0 + ri * 4 + i;
    float y[8];
#pragma unroll
    for (int j = 0; j < 8; ++j) {
      int n = ci * 8 + j;
      y[j] = acc[i][j] + fb2[n] + att[(size_t)row * kE + n];
    }
    float s = 0.f;
#pragma unroll
    for (int j = 0; j < 8; ++j) s += y[j];
    for (int off = 1; off < 16; off <<= 1) s += __shfl_xor(s, off);
    float mean = s * (1.f / 128.f);
    float ssq = 0.f;
#pragma unroll
    for (int j = 0; j < 8; ++j) { float d = y[j] - mean; ssq += d * d; }
    for (int off = 1; off < 16; off <<= 1) ssq += __shfl_xor(ssq, off);
    float inv = 1.f / sqrtf(ssq * (1.f / 128.f) + kEps);
#pragma unroll
    for (int j = 0; j < 8; ++j) {
      int n = ci * 8 + j;
      colsum[j] += (y[j] - mean) * inv * l2g[n] + l2b[n];
    }
  }
#pragma unroll
  for (int j = 0; j < 8; ++j) atomicAdd(&red[ci * 8 + j], colsum[j]);
  __syncthreads();
  if (tid < 128) atomicAdd(&outacc[bb * kE + tid], red[tid]);
}

// ---------------- finalize: /1024 -> out (dtype per flag) ----------------
__global__ void fin_kernel(cfp outacc, const int* __restrict__ flag, void* __restrict__ out) {
  int i = blockIdx.x * 256 + threadIdx.x;
  float v = outacc[i] * (1.f / 1024.f);
  if (*flag) ((float*)out)[i] = v;
  else       ((bf16*)out)[i] = __float2bfloat16(v);
}

extern "C" void kernel_launch(void* const* d_in, const int* in_sizes, int n_in,
                              void* d_out, int out_size, void* d_ws, size_t ws_size,
                              hipStream_t stream) {
  // cumulative offsets for the flat f32 input arena
  CvtArgs args;
  int cum = 0;
  for (int i = 0; i < n_in && i < 27; ++i) {
    args.p[i] = d_in[i];
    args.cum[i] = cum;
    cum += in_sizes[i];
  }
  args.cum[n_in] = cum;
  int total = cum;

  float* ws = (float*)d_ws;
  int* flag    = (int*)ws;              // slot 0..15 reserved
  float* wsin  = ws + 16;               // [total] converted f32 inputs
  float* xsrc  = wsin + total;          // 2097152
  float* att   = xsrc + 2097152;        // 2097152
  float* R     = att + 2097152;         // 8388608: q,k,v,o then reused as ff1
  float* q     = R;
  float* k     = R + 2097152;
  float* v     = R + 4194304;
  float* o     = R + 6291456;
  float* ff1   = R;
  float* outacc = R + 8388608;          // 2048

  const float* wf[27];
  for (int i = 0; i < n_in && i < 27; ++i) wf[i] = wsin + args.cum[i];

  hipMemsetAsync(flag, 0, sizeof(int), stream);
  hipMemsetAsync(outacc, 0, 2048 * sizeof(float), stream);
  detect_kernel<<<(in_sizes[0] + 255) / 256, 256, 0, stream>>>(
      (const unsigned short*)d_in[0], in_sizes[0], flag);
  convert_kernel<<<(total + 255) / 256, 256, 0, stream>>>(args, flag, wsin, total);

  conv_kernel<<<256, 256, 0, stream>>>(wf[0], wf[1], wf[2], wf[3], wf[4], wf[5], wf[6],
                                       wf[7], wf[8], wf[9], wf[10], wf[11], wf[12], xsrc);
  qkv_kernel<<<dim3(256, 3), 256, 0, stream>>>(xsrc, wf[13], wf[14], wf[15], q, k, v);
  attn_kernel<<<dim3(4, kH, 16), 256, 0, stream>>>(q, k, v, wf[16], o);
  ln_kernel<<<4096, 256, 0, stream>>>(o, xsrc, wf[17], wf[18], wf[19], wf[20], att);
  ff1_kernel<<<dim3(256, 4), 256, 0, stream>>>(att, wf[21], wf[22], ff1);
  ff2_kernel<<<256, 256, 0, stream>>>(ff1, att, wf[23], wf[24], wf[25], wf[26], outacc);
  fin_kernel<<<8, 256, 0, stream>>>(outacc, flag, d_out);
}

// Round 3
// 731.914 us; speedup vs baseline: 4.5481x; 4.5481x over previous
//
#include <hip/hip_runtime.h>
#include <hip/hip_bf16.h>
#include <math.h>

using bf16 = __hip_bfloat16;
typedef unsigned short u16;
typedef unsigned int u32;
typedef const float* __restrict__ cfp;

typedef __attribute__((ext_vector_type(8))) short short8v;
typedef __attribute__((ext_vector_type(4))) float f32x4;

static constexpr int kS = 1024, kE = 128, kH = 8, kDH = 16, kDFF = 512;
static constexpr float kEps = 1e-5f;

__device__ __forceinline__ float geluf(float x) { return 0.5f * x * (1.f + erff(x * 0.70710678118654752f)); }
__device__ __forceinline__ u16 f2b(float f) {
  u32 u = __float_as_uint(f);
  u32 r = (u + 0x7FFFu + ((u >> 16) & 1u)) >> 16;
  return (u16)r;
}
__device__ __forceinline__ float b2f_lo(u32 u) { return __uint_as_float(u << 16); }
__device__ __forceinline__ float b2f_hi(u32 u) { return __uint_as_float(u & 0xFFFF0000u); }

// ---------------- dtype detection (inputs bf16 vs f32) ----------------
__global__ void detect_kernel(const u16* __restrict__ xb, int n, int* __restrict__ flag) {
  int i = blockIdx.x * 256 + threadIdx.x;
  if (i >= n) return;
  int e = (xb[i] >> 7) & 0xFF;
  if (e >= 0xB5) *flag = 1;
}

struct CvtArgs { const void* p[27]; int cum[28]; };

__global__ void convert_kernel(CvtArgs a, const int* __restrict__ flag,
                               float* __restrict__ out, int total) {
  int idx = blockIdx.x * 256 + threadIdx.x;
  if (idx >= total) return;
  int id = 0;
  while (idx >= a.cum[id + 1]) ++id;
  int local = idx - a.cum[id];
  float v;
  if (*flag) v = ((const float*)a.p[id])[local];
  else       v = __bfloat162float(((const bf16*)a.p[id])[local]);
  out[idx] = v;
}

// =====================================================================
// Unified bf16 MFMA GEMM: C[M,N] = A[M,K] * W[N,K]^T (+ fused epilogues)
// Tile: BM=128, BN=64, BK=64; 4 waves (2x2), wave tile 64x32.
// ASRC: 0 = conv1+bn1+gelu built on the fly (Ap = x f32)
//       1 = f32 row-major             (FF1: A = att)
//       2 = f32 row-major + tAPE PE   (QKV: A = xsrc)
//       3 = bf16 row-major            (FF2: A = ff1b)
// MODE: 0 conv epi (+c2b,bn2,gelu -> xsrc f32)
//       1 qkv epi  (scatter [b,h,s,d] bf16)
//       2 ff1 epi  (relu(+b1) -> bf16)
//       3 ff2 epi  (+b2 + residual -> f32)
// =====================================================================
template<int ASRC, int MODE, int KTOT>
__global__ __launch_bounds__(256, 4) void gemm_kernel(
    const void* __restrict__ Ap, cfp Wf,
    cfp p0, cfp p1, cfp p2, cfp p3, cfp p4, cfp p5,
    cfp p6, cfp p7, cfp p8, cfp p9, cfp p10,
    void* __restrict__ Out, cfp res) {
  __shared__ short8v Ab[1024];   // 128 x 64 bf16, XOR-swizzled
  __shared__ short8v Bb[512];    //  64 x 64 bf16, XOR-swizzled
  __shared__ float xs[4][136];   // conv halo (ASRC==0)

  int tid = threadIdx.x;
  int mtile = blockIdx.x, ntile = blockIdx.y;
  int bb = (mtile * 128) >> 10;
  int s0 = (mtile * 128) & 1023;

  if (ASRC == 0) {
    for (int t = tid; t < 136; t += 256) {
      int gs = s0 - 3 + t;
      float4 xv = (gs >= 0 && gs < kS) ? ((const float4*)Ap)[bb * kS + gs]
                                       : make_float4(0.f, 0.f, 0.f, 0.f);
      xs[0][t] = xv.x; xs[1][t] = xv.y; xs[2][t] = xv.z; xs[3][t] = xv.w;
    }
  }

  int wid = tid >> 6, lane = tid & 63;
  int m0w = (wid >> 1) * 64, n0w = (wid & 1) * 32;
  int lrow = lane & 15, lk = lane >> 4;

  f32x4 acc[4][2];
#pragma unroll
  for (int mi = 0; mi < 4; ++mi)
#pragma unroll
    for (int ni = 0; ni < 2; ++ni) acc[mi][ni] = (f32x4){0.f, 0.f, 0.f, 0.f};

  for (int k0 = 0; k0 < KTOT; k0 += 64) {
    __syncthreads();
    // ---- stage A tile (128 x 64) ----
#pragma unroll
    for (int c = 0; c < 4; ++c) {
      int chunk = tid + 256 * c;
      int row = chunk >> 3, kc = chunk & 7;
      int grow = mtile * 128 + row;
      u32 off = ((u32)(row * 128 + kc * 16)) ^ ((u32)((row & 7) << 4));
      if (ASRC == 3) {
        const u16* As = (const u16*)Ap + (size_t)grow * KTOT + k0 + kc * 8;
        Ab[off >> 4] = *(const short8v*)As;
      } else {
        float tv[8];
        if (ASRC == 0) {
          int kg8 = k0 + kc * 8;
          int c1 = kg8 >> 2;     // covers c1, c1+1 (r = 0..3 each)
#pragma unroll
          for (int cc = 0; cc < 2; ++cc) {
            int cx = c1 + cc;
            const float* w1r = p0 + cx * 8;
            float sc = p2[cx] * __frsqrt_rn(p5[cx] + kEps);
            float ofs = p3[cx] - p4[cx] * sc;
            float cb = p1[cx];
#pragma unroll
            for (int r = 0; r < 4; ++r) {
              float h = cb;
#pragma unroll
              for (int t = 0; t < 8; ++t) h += xs[r][row + t] * w1r[t];
              tv[cc * 4 + r] = geluf(h * sc + ofs);
            }
          }
        } else {
          const float* Af = (const float*)Ap + (size_t)grow * KTOT + k0 + kc * 8;
          float4 xa = *(const float4*)Af;
          float4 xb = *(const float4*)(Af + 4);
          tv[0] = xa.x; tv[1] = xa.y; tv[2] = xa.z; tv[3] = xa.w;
          tv[4] = xb.x; tv[5] = xb.y; tv[6] = xb.z; tv[7] = xb.w;
          if (ASRC == 2) {
            int s = grow & 1023;
#pragma unroll
            for (int e = 0; e < 8; ++e) {
              int kg = k0 + kc * 8 + e;
              float div = __expf((float)(kg >> 1) * (-0.14391156824963732f));
              float ang = (float)s * div * 0.125f;
              tv[e] += (kg & 1) ? __cosf(ang) : __sinf(ang);
            }
          }
        }
        short8v sv;
#pragma unroll
        for (int e = 0; e < 8; ++e) sv[e] = (short)f2b(tv[e]);
        Ab[off >> 4] = sv;
      }
    }
    // ---- stage B tile (64 x 64) from f32 weights ----
#pragma unroll
    for (int c = 0; c < 2; ++c) {
      int chunk = tid + 256 * c;
      int row = chunk >> 3, kc = chunk & 7;
      const float* Wp = Wf + (size_t)(ntile * 64 + row) * KTOT + k0 + kc * 8;
      float4 xa = *(const float4*)Wp;
      float4 xb = *(const float4*)(Wp + 4);
      short8v sv;
      sv[0] = (short)f2b(xa.x); sv[1] = (short)f2b(xa.y);
      sv[2] = (short)f2b(xa.z); sv[3] = (short)f2b(xa.w);
      sv[4] = (short)f2b(xb.x); sv[5] = (short)f2b(xb.y);
      sv[6] = (short)f2b(xb.z); sv[7] = (short)f2b(xb.w);
      u32 off = ((u32)(row * 128 + kc * 16)) ^ ((u32)((row & 7) << 4));
      Bb[off >> 4] = sv;
    }
    __syncthreads();
    // ---- MFMA ----
#pragma unroll
    for (int ks = 0; ks < 2; ++ks) {
      short8v af[4], bfr[2];
#pragma unroll
      for (int mi = 0; mi < 4; ++mi) {
        int row = m0w + mi * 16 + lrow;
        u32 off = ((u32)(row * 128 + ks * 64 + lk * 16)) ^ ((u32)((row & 7) << 4));
        af[mi] = Ab[off >> 4];
      }
#pragma unroll
      for (int ni = 0; ni < 2; ++ni) {
        int row = n0w + ni * 16 + lrow;
        u32 off = ((u32)(row * 128 + ks * 64 + lk * 16)) ^ ((u32)((row & 7) << 4));
        bfr[ni] = Bb[off >> 4];
      }
#pragma unroll
      for (int mi = 0; mi < 4; ++mi)
#pragma unroll
        for (int ni = 0; ni < 2; ++ni)
          acc[mi][ni] = __builtin_amdgcn_mfma_f32_16x16x32_bf16(af[mi], bfr[ni], acc[mi][ni], 0, 0, 0);
    }
  }

  // ---- epilogue ----
#pragma unroll
  for (int ni = 0; ni < 2; ++ni) {
    int n = ntile * 64 + n0w + ni * 16 + lrow;
    float c0 = 0.f, c1v = 0.f, c2v = 0.f;
    if (MODE == 0) {
      float scn = p7[n] * __frsqrt_rn(p10[n] + kEps);
      c1v = scn;
      c2v = (p6[n] - p9[n]) * scn + p8[n];
    } else if (MODE == 2 || MODE == 3) {
      c0 = p0[n];
    }
#pragma unroll
    for (int mi = 0; mi < 4; ++mi) {
#pragma unroll
      for (int r = 0; r < 4; ++r) {
        int grow = mtile * 128 + m0w + mi * 16 + lk * 4 + r;
        float val = acc[mi][ni][r];
        if (MODE == 0) {
          ((float*)Out)[(size_t)grow * kE + n] = geluf(val * c1v + c2v);
        } else if (MODE == 1) {
          int s = grow & 1023, b_ = grow >> 10;
          ((u16*)Out)[(((size_t)(b_ * kH + (n >> 4))) * kS + s) * kDH + (n & 15)] = f2b(val);
        } else if (MODE == 2) {
          ((u16*)Out)[(size_t)grow * kDFF + n] = f2b(fmaxf(val + c0, 0.f));
        } else {
          ((float*)Out)[(size_t)grow * kE + n] = val + c0 + res[(size_t)grow * kE + n];
        }
      }
    }
  }
}

// ---------------- attention: K/V/rel-bias in LDS, 1 q-row/thread ----------------
__global__ __launch_bounds__(512, 2) void attn_kernel(
    const u16* __restrict__ qb, const u16* __restrict__ kb,
    const u16* __restrict__ vb, cfp relb, float* __restrict__ o) {
  __shared__ __align__(16) u16 Ks[16384];
  __shared__ __align__(16) u16 Vs[16384];
  __shared__ float rb[2048];
  int tid = threadIdx.x;
  int half = blockIdx.x & 1, h = (blockIdx.x >> 1) & 7, bb = blockIdx.x >> 4;
  size_t base = (size_t)(bb * kH + h) * kS * kDH;

  for (int c = tid; c < 2048; c += 512) {
    ((uint4*)Ks)[c] = ((const uint4*)(kb + base))[c];
    ((uint4*)Vs)[c] = ((const uint4*)(vb + base))[c];
  }
  for (int t = tid; t < 2047; t += 512) rb[t] = relb[t * kH + h];
  __syncthreads();

  int i = half * 512 + tid;
  float qr[16];
  {
    const uint4* qp = (const uint4*)(qb + base + (size_t)i * 16);
    uint4 a = qp[0], b = qp[1];
    qr[0] = b2f_lo(a.x); qr[1] = b2f_hi(a.x); qr[2] = b2f_lo(a.y); qr[3] = b2f_hi(a.y);
    qr[4] = b2f_lo(a.z); qr[5] = b2f_hi(a.z); qr[6] = b2f_lo(a.w); qr[7] = b2f_hi(a.w);
    qr[8] = b2f_lo(b.x); qr[9] = b2f_hi(b.x); qr[10] = b2f_lo(b.y); qr[11] = b2f_hi(b.y);
    qr[12] = b2f_lo(b.z); qr[13] = b2f_hi(b.z); qr[14] = b2f_lo(b.w); qr[15] = b2f_hi(b.w);
  }
  const float scale = 0.088388347648318447f;   // 128^-0.5

  float mx = -1e30f;
  for (int j = 0; j < kS; ++j) {
    const uint4* kj = (const uint4*)(Ks + j * 16);
    uint4 a = kj[0], b = kj[1];
    float s = qr[0] * b2f_lo(a.x) + qr[1] * b2f_hi(a.x) + qr[2] * b2f_lo(a.y) + qr[3] * b2f_hi(a.y)
            + qr[4] * b2f_lo(a.z) + qr[5] * b2f_hi(a.z) + qr[6] * b2f_lo(a.w) + qr[7] * b2f_hi(a.w)
            + qr[8] * b2f_lo(b.x) + qr[9] * b2f_hi(b.x) + qr[10] * b2f_lo(b.y) + qr[11] * b2f_hi(b.y)
            + qr[12] * b2f_lo(b.z) + qr[13] * b2f_hi(b.z) + qr[14] * b2f_lo(b.w) + qr[15] * b2f_hi(b.w);
    mx = fmaxf(mx, s);
  }
  mx *= scale;

  float l = 0.f, accv[16], accb[16];
#pragma unroll
  for (int d = 0; d < 16; ++d) { accv[d] = 0.f; accb[d] = 0.f; }
  const float* rbp = rb + i + 1023;
  for (int j = 0; j < kS; ++j) {
    const uint4* kj = (const uint4*)(Ks + j * 16);
    uint4 a = kj[0], b = kj[1];
    float s = qr[0] * b2f_lo(a.x) + qr[1] * b2f_hi(a.x) + qr[2] * b2f_lo(a.y) + qr[3] * b2f_hi(a.y)
            + qr[4] * b2f_lo(a.z) + qr[5] * b2f_hi(a.z) + qr[6] * b2f_lo(a.w) + qr[7] * b2f_hi(a.w)
            + qr[8] * b2f_lo(b.x) + qr[9] * b2f_hi(b.x) + qr[10] * b2f_lo(b.y) + qr[11] * b2f_hi(b.y)
            + qr[12] * b2f_lo(b.z) + qr[13] * b2f_hi(b.z) + qr[14] * b2f_lo(b.w) + qr[15] * b2f_hi(b.w);
    float e = __expf(s * scale - mx);
    l += e;
    float wb = rbp[-j];
    const uint4* vj = (const uint4*)(Vs + j * 16);
    uint4 va = vj[0], vb4 = vj[1];
    float vf[16];
    vf[0] = b2f_lo(va.x); vf[1] = b2f_hi(va.x); vf[2] = b2f_lo(va.y); vf[3] = b2f_hi(va.y);
    vf[4] = b2f_lo(va.z); vf[5] = b2f_hi(va.z); vf[6] = b2f_lo(va.w); vf[7] = b2f_hi(va.w);
    vf[8] = b2f_lo(vb4.x); vf[9] = b2f_hi(vb4.x); vf[10] = b2f_lo(vb4.y); vf[11] = b2f_hi(vb4.y);
    vf[12] = b2f_lo(vb4.z); vf[13] = b2f_hi(vb4.z); vf[14] = b2f_lo(vb4.w); vf[15] = b2f_hi(vb4.w);
#pragma unroll
    for (int d = 0; d < 16; ++d) {
      accv[d] += e * vf[d];
      accb[d] += wb * vf[d];
    }
  }
  float inv = 1.f / l;
  float* orow = o + ((size_t)(bb * kS + i)) * kE + h * kDH;
#pragma unroll
  for (int d = 0; d < 16; ++d) orow[d] = accv[d] * inv + accb[d];
}

// ---------------- LN(attn out) + residual + LN1 -> att ----------------
__global__ __launch_bounds__(256) void ln_kernel(
    cfp o, cfp xsrc, cfp lag, cfp lab, cfp l1g, cfp l1b, float* __restrict__ att) {
  int row = blockIdx.x * 4 + (threadIdx.x >> 6);
  int lane = threadIdx.x & 63;
  float2 a = ((const float2*)(o + (size_t)row * kE))[lane];
  float sum = a.x + a.y;
  for (int off = 1; off < 64; off <<= 1) sum += __shfl_xor(sum, off);
  float mean = sum * (1.f / 128.f);
  float d0 = a.x - mean, d1 = a.y - mean;
  float ss = d0 * d0 + d1 * d1;
  for (int off = 1; off < 64; off <<= 1) ss += __shfl_xor(ss, off);
  float inv = 1.f / sqrtf(ss * (1.f / 128.f) + kEps);
  float t0 = d0 * inv * lag[2 * lane] + lab[2 * lane];
  float t1 = d1 * inv * lag[2 * lane + 1] + lab[2 * lane + 1];
  float2 xv = ((const float2*)(xsrc + (size_t)row * kE))[lane];
  t0 += xv.x; t1 += xv.y;
  float sum2 = t0 + t1;
  for (int off = 1; off < 64; off <<= 1) sum2 += __shfl_xor(sum2, off);
  float mean2 = sum2 * (1.f / 128.f);
  float e0 = t0 - mean2, e1 = t1 - mean2;
  float ss2 = e0 * e0 + e1 * e1;
  for (int off = 1; off < 64; off <<= 1) ss2 += __shfl_xor(ss2, off);
  float inv2 = 1.f / sqrtf(ss2 * (1.f / 128.f) + kEps);
  float r0 = e0 * inv2 * l1g[2 * lane] + l1b[2 * lane];
  float r1 = e1 * inv2 * l1g[2 * lane + 1] + l1b[2 * lane + 1];
  ((float2*)(att + (size_t)row * kE))[lane] = make_float2(r0, r1);
}

// ---------------- LN2 + GAP ----------------
__global__ __launch_bounds__(256) void ln2gap_kernel(
    cfp yff, cfp l2g, cfp l2b, float* __restrict__ outacc) {
  __shared__ float red[128];
  int tid = threadIdx.x;
  if (tid < 128) red[tid] = 0.f;
  __syncthreads();
  int row = blockIdx.x * 4 + (tid >> 6);
  int lane = tid & 63;
  float2 a = ((const float2*)(yff + (size_t)row * kE))[lane];
  float sum = a.x + a.y;
  for (int off = 1; off < 64; off <<= 1) sum += __shfl_xor(sum, off);
  float mean = sum * (1.f / 128.f);
  float d0 = a.x - mean, d1 = a.y - mean;
  float ss = d0 * d0 + d1 * d1;
  for (int off = 1; off < 64; off <<= 1) ss += __shfl_xor(ss, off);
  float inv = 1.f / sqrtf(ss * (1.f / 128.f) + kEps);
  float r0 = d0 * inv * l2g[2 * lane] + l2b[2 * lane];
  float r1 = d1 * inv * l2g[2 * lane + 1] + l2b[2 * lane + 1];
  atomicAdd(&red[2 * lane], r0);
  atomicAdd(&red[2 * lane + 1], r1);
  __syncthreads();
  int bb = (blockIdx.x * 4) >> 10;
  if (tid < 128) atomicAdd(&outacc[bb * kE + tid], red[tid]);
}

// ---------------- finalize ----------------
__global__ void fin_kernel(cfp outacc, const int* __restrict__ flag, void* __restrict__ out) {
  int i = blockIdx.x * 256 + threadIdx.x;
  float v = outacc[i] * (1.f / 1024.f);
  if (*flag) ((float*)out)[i] = v;
  else       ((bf16*)out)[i] = __float2bfloat16(v);
}

extern "C" void kernel_launch(void* const* d_in, const int* in_sizes, int n_in,
                              void* d_out, int out_size, void* d_ws, size_t ws_size,
                              hipStream_t stream) {
  CvtArgs args;
  int cum = 0;
  for (int i = 0; i < n_in && i < 27; ++i) {
    args.p[i] = d_in[i];
    args.cum[i] = cum;
    cum += in_sizes[i];
  }
  args.cum[n_in] = cum;
  int total = cum;
  int totalPad = (total + 15) & ~15;

  float* ws = (float*)d_ws;
  int* flag    = (int*)ws;                       // 16 slots
  float* wsinf = ws + 16;                        // f32 input arena
  float* xsrc  = wsinf + totalPad;               // 2,097,152
  float* att   = xsrc + 2097152;                 // 2,097,152
  float* qkv0  = att + 2097152;                  // 3,145,728 (q,k,v bf16)
  float* ext   = qkv0 + 3145728;                 // 1,048,576 (ff1b tail)
  float* o     = ext + 1048576;                  // 2,097,152 (later yff)
  float* outacc = o + 2097152;                   // 2,048

  u16* qb = (u16*)qkv0;
  u16* kb = qb + 2097152;
  u16* vb = kb + 2097152;
  u16* ff1b = (u16*)qkv0;                        // spans qkv0 + ext
  float* yff = o;

  const float* wf[27];
  for (int i = 0; i < n_in && i < 27; ++i) wf[i] = wsinf + args.cum[i];

  hipMemsetAsync(flag, 0, sizeof(int), stream);
  hipMemsetAsync(outacc, 0, 2048 * sizeof(float), stream);
  detect_kernel<<<(in_sizes[0] + 255) / 256, 256, 0, stream>>>(
      (const u16*)d_in[0], in_sizes[0], flag);
  convert_kernel<<<(total + 255) / 256, 256, 0, stream>>>(args, flag, wsinf, total);

  // conv1+bn1+gelu+conv2+bn2+gelu
  gemm_kernel<0, 0, 2048><<<dim3(128, 2), 256, 0, stream>>>(
      wf[0], wf[7], wf[1], wf[2], wf[3], wf[4], wf[5], wf[6],
      wf[8], wf[9], wf[10], wf[11], wf[12], xsrc, nullptr);
  // QKV (PE added in staging)
  gemm_kernel<2, 1, 128><<<dim3(128, 2), 256, 0, stream>>>(
      xsrc, wf[13], nullptr, nullptr, nullptr, nullptr, nullptr, nullptr,
      nullptr, nullptr, nullptr, nullptr, nullptr, qb, nullptr);
  gemm_kernel<2, 1, 128><<<dim3(128, 2), 256, 0, stream>>>(
      xsrc, wf[14], nullptr, nullptr, nullptr, nullptr, nullptr, nullptr,
      nullptr, nullptr, nullptr, nullptr, nullptr, kb, nullptr);
  gemm_kernel<2, 1, 128><<<dim3(128, 2), 256, 0, stream>>>(
      xsrc, wf[15], nullptr, nullptr, nullptr, nullptr, nullptr, nullptr,
      nullptr, nullptr, nullptr, nullptr, nullptr, vb, nullptr);

  attn_kernel<<<256, 512, 0, stream>>>(qb, kb, vb, wf[16], o);
  ln_kernel<<<4096, 256, 0, stream>>>(o, xsrc, wf[17], wf[18], wf[19], wf[20], att);

  gemm_kernel<1, 2, 128><<<dim3(128, 8), 256, 0, stream>>>(
      att, wf[21], wf[22], nullptr, nullptr, nullptr, nullptr, nullptr,
      nullptr, nullptr, nullptr, nullptr, nullptr, ff1b, nullptr);
  gemm_kernel<3, 3, 512><<<dim3(128, 2), 256, 0, stream>>>(
      ff1b, wf[23], wf[24], nullptr, nullptr, nullptr, nullptr, nullptr,
      nullptr, nullptr, nullptr, nullptr, nullptr, yff, att);

  ln2gap_kernel<<<4096, 256, 0, stream>>>(yff, wf[25], wf[26], outacc);
  fin_kernel<<<8, 256, 0, stream>>>(outacc, flag, d_out);
}

// Round 4
// 355.625 us; speedup vs baseline: 9.3606x; 2.0581x over previous
//
#include <hip/hip_runtime.h>
#include <hip/hip_bf16.h>
#include <math.h>

using bf16 = __hip_bfloat16;
typedef unsigned short u16;
typedef unsigned int u32;
typedef const float* __restrict__ cfp;

typedef __attribute__((ext_vector_type(8))) short short8v;
typedef __attribute__((ext_vector_type(4))) float f32x4;

static constexpr int kS = 1024, kE = 128, kH = 8, kDH = 16, kDFF = 512;
static constexpr float kEps = 1e-5f;

__device__ __forceinline__ float geluf(float x) { return 0.5f * x * (1.f + erff(x * 0.70710678118654752f)); }
__device__ __forceinline__ u16 f2b(float f) {
  u32 u = __float_as_uint(f);
  u32 r = (u + 0x7FFFu + ((u >> 16) & 1u)) >> 16;
  return (u16)r;
}
__device__ __forceinline__ float b2f_lo(u32 u) { return __uint_as_float(u << 16); }
__device__ __forceinline__ float b2f_hi(u32 u) { return __uint_as_float(u & 0xFFFF0000u); }

// ---------------- dtype detection (inputs bf16 vs f32) ----------------
__global__ void detect_kernel(const u16* __restrict__ xb, int n, int* __restrict__ flag) {
  int i = blockIdx.x * 256 + threadIdx.x;
  if (i >= n) return;
  int e = (xb[i] >> 7) & 0xFF;
  if (e >= 0xB5) *flag = 1;
}

struct CvtArgs { const void* p[27]; int cum[28]; };

__global__ void convert_kernel(CvtArgs a, const int* __restrict__ flag,
                               float* __restrict__ out, int total) {
  int idx = blockIdx.x * 256 + threadIdx.x;
  if (idx >= total) return;
  int id = 0;
  while (idx >= a.cum[id + 1]) ++id;
  int local = idx - a.cum[id];
  float v;
  if (*flag) v = ((const float*)a.p[id])[local];
  else       v = __bfloat162float(((const bf16*)a.p[id])[local]);
  out[idx] = v;
}

// =====================================================================
// Unified bf16 MFMA GEMM (unchanged from round 3 — passed)
// =====================================================================
template<int ASRC, int MODE, int KTOT>
__global__ __launch_bounds__(256, 4) void gemm_kernel(
    const void* __restrict__ Ap, cfp Wf,
    cfp p0, cfp p1, cfp p2, cfp p3, cfp p4, cfp p5,
    cfp p6, cfp p7, cfp p8, cfp p9, cfp p10,
    void* __restrict__ Out, cfp res) {
  __shared__ short8v Ab[1024];   // 128 x 64 bf16, XOR-swizzled
  __shared__ short8v Bb[512];    //  64 x 64 bf16, XOR-swizzled
  __shared__ float xs[4][136];   // conv halo (ASRC==0)

  int tid = threadIdx.x;
  int mtile = blockIdx.x, ntile = blockIdx.y;
  int bb = (mtile * 128) >> 10;
  int s0 = (mtile * 128) & 1023;

  if (ASRC == 0) {
    for (int t = tid; t < 136; t += 256) {
      int gs = s0 - 3 + t;
      float4 xv = (gs >= 0 && gs < kS) ? ((const float4*)Ap)[bb * kS + gs]
                                       : make_float4(0.f, 0.f, 0.f, 0.f);
      xs[0][t] = xv.x; xs[1][t] = xv.y; xs[2][t] = xv.z; xs[3][t] = xv.w;
    }
  }

  int wid = tid >> 6, lane = tid & 63;
  int m0w = (wid >> 1) * 64, n0w = (wid & 1) * 32;
  int lrow = lane & 15, lk = lane >> 4;

  f32x4 acc[4][2];
#pragma unroll
  for (int mi = 0; mi < 4; ++mi)
#pragma unroll
    for (int ni = 0; ni < 2; ++ni) acc[mi][ni] = (f32x4){0.f, 0.f, 0.f, 0.f};

  for (int k0 = 0; k0 < KTOT; k0 += 64) {
    __syncthreads();
#pragma unroll
    for (int c = 0; c < 4; ++c) {
      int chunk = tid + 256 * c;
      int row = chunk >> 3, kc = chunk & 7;
      int grow = mtile * 128 + row;
      u32 off = ((u32)(row * 128 + kc * 16)) ^ ((u32)((row & 7) << 4));
      if (ASRC == 3) {
        const u16* As = (const u16*)Ap + (size_t)grow * KTOT + k0 + kc * 8;
        Ab[off >> 4] = *(const short8v*)As;
      } else {
        float tv[8];
        if (ASRC == 0) {
          int kg8 = k0 + kc * 8;
          int c1 = kg8 >> 2;
#pragma unroll
          for (int cc = 0; cc < 2; ++cc) {
            int cx = c1 + cc;
            const float* w1r = p0 + cx * 8;
            float sc = p2[cx] * __frsqrt_rn(p5[cx] + kEps);
            float ofs = p3[cx] - p4[cx] * sc;
            float cb = p1[cx];
#pragma unroll
            for (int r = 0; r < 4; ++r) {
              float h = cb;
#pragma unroll
              for (int t = 0; t < 8; ++t) h += xs[r][row + t] * w1r[t];
              tv[cc * 4 + r] = geluf(h * sc + ofs);
            }
          }
        } else {
          const float* Af = (const float*)Ap + (size_t)grow * KTOT + k0 + kc * 8;
          float4 xa = *(const float4*)Af;
          float4 xb = *(const float4*)(Af + 4);
          tv[0] = xa.x; tv[1] = xa.y; tv[2] = xa.z; tv[3] = xa.w;
          tv[4] = xb.x; tv[5] = xb.y; tv[6] = xb.z; tv[7] = xb.w;
          if (ASRC == 2) {
            int s = grow & 1023;
#pragma unroll
            for (int e = 0; e < 8; ++e) {
              int kg = k0 + kc * 8 + e;
              float div = __expf((float)(kg >> 1) * (-0.14391156824963732f));
              float ang = (float)s * div * 0.125f;
              tv[e] += (kg & 1) ? __cosf(ang) : __sinf(ang);
            }
          }
        }
        short8v sv;
#pragma unroll
        for (int e = 0; e < 8; ++e) sv[e] = (short)f2b(tv[e]);
        Ab[off >> 4] = sv;
      }
    }
#pragma unroll
    for (int c = 0; c < 2; ++c) {
      int chunk = tid + 256 * c;
      int row = chunk >> 3, kc = chunk & 7;
      const float* Wp = Wf + (size_t)(ntile * 64 + row) * KTOT + k0 + kc * 8;
      float4 xa = *(const float4*)Wp;
      float4 xb = *(const float4*)(Wp + 4);
      short8v sv;
      sv[0] = (short)f2b(xa.x); sv[1] = (short)f2b(xa.y);
      sv[2] = (short)f2b(xa.z); sv[3] = (short)f2b(xa.w);
      sv[4] = (short)f2b(xb.x); sv[5] = (short)f2b(xb.y);
      sv[6] = (short)f2b(xb.z); sv[7] = (short)f2b(xb.w);
      u32 off = ((u32)(row * 128 + kc * 16)) ^ ((u32)((row & 7) << 4));
      Bb[off >> 4] = sv;
    }
    __syncthreads();
#pragma unroll
    for (int ks = 0; ks < 2; ++ks) {
      short8v af[4], bfr[2];
#pragma unroll
      for (int mi = 0; mi < 4; ++mi) {
        int row = m0w + mi * 16 + lrow;
        u32 off = ((u32)(row * 128 + ks * 64 + lk * 16)) ^ ((u32)((row & 7) << 4));
        af[mi] = Ab[off >> 4];
      }
#pragma unroll
      for (int ni = 0; ni < 2; ++ni) {
        int row = n0w + ni * 16 + lrow;
        u32 off = ((u32)(row * 128 + ks * 64 + lk * 16)) ^ ((u32)((row & 7) << 4));
        bfr[ni] = Bb[off >> 4];
      }
#pragma unroll
      for (int mi = 0; mi < 4; ++mi)
#pragma unroll
        for (int ni = 0; ni < 2; ++ni)
          acc[mi][ni] = __builtin_amdgcn_mfma_f32_16x16x32_bf16(af[mi], bfr[ni], acc[mi][ni], 0, 0, 0);
    }
  }

#pragma unroll
  for (int ni = 0; ni < 2; ++ni) {
    int n = ntile * 64 + n0w + ni * 16 + lrow;
    float c0 = 0.f, c1v = 0.f, c2v = 0.f;
    if (MODE == 0) {
      float scn = p7[n] * __frsqrt_rn(p10[n] + kEps);
      c1v = scn;
      c2v = (p6[n] - p9[n]) * scn + p8[n];
    } else if (MODE == 2 || MODE == 3) {
      c0 = p0[n];
    }
#pragma unroll
    for (int mi = 0; mi < 4; ++mi) {
#pragma unroll
      for (int r = 0; r < 4; ++r) {
        int grow = mtile * 128 + m0w + mi * 16 + lk * 4 + r;
        float val = acc[mi][ni][r];
        if (MODE == 0) {
          ((float*)Out)[(size_t)grow * kE + n] = geluf(val * c1v + c2v);
        } else if (MODE == 1) {
          int s = grow & 1023, b_ = grow >> 10;
          ((u16*)Out)[(((size_t)(b_ * kH + (n >> 4))) * kS + s) * kDH + (n & 15)] = f2b(val);
        } else if (MODE == 2) {
          ((u16*)Out)[(size_t)grow * kDFF + n] = f2b(fmaxf(val + c0, 0.f));
        } else {
          ((float*)Out)[(size_t)grow * kE + n] = val + c0 + res[(size_t)grow * kE + n];
        }
      }
    }
  }
}

// =====================================================================
// MFMA attention. grid 512 = (b,h,quarter); block 512 = 8 waves.
// Wave owns 32 query rows (2 q-tiles of 16). Per 32-key step:
//   2x QK mfma (head-dim 16 zero-padded to K=32), exp (no-max softmax),
//   P->bf16 into wave-private LDS tile, 2x PV mfma (e*V and relbias*V).
// O = O_e / l + O_rb.
// =====================================================================
__global__ __launch_bounds__(512, 4) void attn_kernel(
    const u16* __restrict__ qb, const u16* __restrict__ kb,
    const u16* __restrict__ vb, cfp relb, float* __restrict__ o) {
  __shared__ u16 Ksh[1024 * 16];   // [j][d] row-major, 32B rows     (32768B)
  __shared__ u16 Vsh[16 * 1032];   // Vt[d][j], row stride 1032      (33024B)
  __shared__ u16 rbf[2048];        // rel bias (bf16), fwd order     (4096B)
  __shared__ u16 Pt[8][640];       // per-wave P tile [16][40]       (10240B)

  int tid = threadIdx.x;
  int quarter = blockIdx.x & 3;
  int h = (blockIdx.x >> 2) & 7;
  int bb = blockIdx.x >> 5;
  size_t base = (size_t)(bb * kH + h) * (kS * kDH);

  for (int j = tid; j < 1024; j += 512) {
    const uint4* src = (const uint4*)(kb + base + j * 16);
    ((uint4*)Ksh)[j * 2] = src[0];
    ((uint4*)Ksh)[j * 2 + 1] = src[1];
  }
  for (int j = tid; j < 1024; j += 512) {
    const uint4* src = (const uint4*)(vb + base + j * 16);
    uint4 a = src[0], b = src[1];
    u32 wv[8] = {a.x, a.y, a.z, a.w, b.x, b.y, b.z, b.w};
#pragma unroll
    for (int p = 0; p < 8; ++p) {
      Vsh[(2 * p) * 1032 + j]     = (u16)(wv[p] & 0xFFFFu);
      Vsh[(2 * p + 1) * 1032 + j] = (u16)(wv[p] >> 16);
    }
  }
  for (int t = tid; t < 2047; t += 512) rbf[t] = f2b(relb[t * kH + h]);
  if (tid == 0) rbf[2047] = 0;
  __syncthreads();

  int w = tid >> 6, l = tid & 63;
  int lr = l & 15, lg = l >> 4;      // lg in 0..3
  u16* P = Pt[w];
  int qbase = quarter * 256 + w * 32;
  const float kScaleLn = 0.088388347648318447f;  // 128^-0.5

  for (int qt = 0; qt < 2; ++qt) {
    int q0 = qbase + qt * 16;
    short8v qf = (short8v){0, 0, 0, 0, 0, 0, 0, 0};
    if (lg < 2)
      qf = *(const short8v*)(qb + base + (size_t)(q0 + lr) * 16 + lg * 8);
    f32x4 acc_e = (f32x4){0.f, 0.f, 0.f, 0.f};
    f32x4 acc_rb = (f32x4){0.f, 0.f, 0.f, 0.f};
    float lac[4] = {0.f, 0.f, 0.f, 0.f};

    for (int jb = 0; jb < 32; ++jb) {
#pragma unroll
      for (int hh = 0; hh < 2; ++hh) {
        int kb16 = jb * 2 + hh;
        short8v kf = (short8v){0, 0, 0, 0, 0, 0, 0, 0};
        if (lg < 2)
          kf = *(const short8v*)(Ksh + (kb16 * 16 + lr) * 16 + lg * 8);
        f32x4 s = __builtin_amdgcn_mfma_f32_16x16x32_bf16(
            qf, kf, (f32x4){0.f, 0.f, 0.f, 0.f}, 0, 0, 0);
        int colb = hh * 16 + lr;
#pragma unroll
        for (int r = 0; r < 4; ++r) {
          float e = __expf(s[r] * kScaleLn);
          lac[r] += e;
          P[(lg * 4 + r) * 40 + colb] = f2b(e);
        }
      }
      // PV over 32 keys (same-wave LDS RAW; compiler inserts lgkmcnt)
      short8v pf = *(const short8v*)(P + lr * 40 + lg * 8);
      short8v vf = *(const short8v*)(Vsh + lr * 1032 + jb * 32 + lg * 8);
      acc_e = __builtin_amdgcn_mfma_f32_16x16x32_bf16(pf, vf, acc_e, 0, 0, 0);
      int t0 = q0 + lr - jb * 32 - lg * 8 + 1023;
      short8v rf;
#pragma unroll
      for (int e = 0; e < 8; ++e) rf[e] = (short)rbf[t0 - e];
      acc_rb = __builtin_amdgcn_mfma_f32_16x16x32_bf16(rf, vf, acc_rb, 0, 0, 0);
    }

#pragma unroll
    for (int r = 0; r < 4; ++r) {
      lac[r] += __shfl_xor(lac[r], 1);
      lac[r] += __shfl_xor(lac[r], 2);
      lac[r] += __shfl_xor(lac[r], 4);
      lac[r] += __shfl_xor(lac[r], 8);
    }
#pragma unroll
    for (int r = 0; r < 4; ++r) {
      float inv = 1.f / lac[r];
      int row = q0 + lg * 4 + r;
      o[(size_t)(bb * kS + row) * kE + h * kDH + lr] = acc_e[r] * inv + acc_rb[r];
    }
  }
}

// ---------------- LN(attn out) + residual + LN1 -> att ----------------
__global__ __launch_bounds__(256) void ln_kernel(
    cfp o, cfp xsrc, cfp lag, cfp lab, cfp l1g, cfp l1b, float* __restrict__ att) {
  int row = blockIdx.x * 4 + (threadIdx.x >> 6);
  int lane = threadIdx.x & 63;
  float2 a = ((const float2*)(o + (size_t)row * kE))[lane];
  float sum = a.x + a.y;
  for (int off = 1; off < 64; off <<= 1) sum += __shfl_xor(sum, off);
  float mean = sum * (1.f / 128.f);
  float d0 = a.x - mean, d1 = a.y - mean;
  float ss = d0 * d0 + d1 * d1;
  for (int off = 1; off < 64; off <<= 1) ss += __shfl_xor(ss, off);
  float inv = 1.f / sqrtf(ss * (1.f / 128.f) + kEps);
  float t0 = d0 * inv * lag[2 * lane] + lab[2 * lane];
  float t1 = d1 * inv * lag[2 * lane + 1] + lab[2 * lane + 1];
  float2 xv = ((const float2*)(xsrc + (size_t)row * kE))[lane];
  t0 += xv.x; t1 += xv.y;
  float sum2 = t0 + t1;
  for (int off = 1; off < 64; off <<= 1) sum2 += __shfl_xor(sum2, off);
  float mean2 = sum2 * (1.f / 128.f);
  float e0 = t0 - mean2, e1 = t1 - mean2;
  float ss2 = e0 * e0 + e1 * e1;
  for (int off = 1; off < 64; off <<= 1) ss2 += __shfl_xor(ss2, off);
  float inv2 = 1.f / sqrtf(ss2 * (1.f / 128.f) + kEps);
  float r0 = e0 * inv2 * l1g[2 * lane] + l1b[2 * lane];
  float r1 = e1 * inv2 * l1g[2 * lane + 1] + l1b[2 * lane + 1];
  ((float2*)(att + (size_t)row * kE))[lane] = make_float2(r0, r1);
}

// ---------------- LN2 + GAP ----------------
__global__ __launch_bounds__(256) void ln2gap_kernel(
    cfp yff, cfp l2g, cfp l2b, float* __restrict__ outacc) {
  __shared__ float red[128];
  int tid = threadIdx.x;
  if (tid < 128) red[tid] = 0.f;
  __syncthreads();
  int row = blockIdx.x * 4 + (tid >> 6);
  int lane = tid & 63;
  float2 a = ((const float2*)(yff + (size_t)row * kE))[lane];
  float sum = a.x + a.y;
  for (int off = 1; off < 64; off <<= 1) sum += __shfl_xor(sum, off);
  float mean = sum * (1.f / 128.f);
  float d0 = a.x - mean, d1 = a.y - mean;
  float ss = d0 * d0 + d1 * d1;
  for (int off = 1; off < 64; off <<= 1) ss += __shfl_xor(ss, off);
  float inv = 1.f / sqrtf(ss * (1.f / 128.f) + kEps);
  float r0 = d0 * inv * l2g[2 * lane] + l2b[2 * lane];
  float r1 = d1 * inv * l2g[2 * lane + 1] + l2b[2 * lane + 1];
  atomicAdd(&red[2 * lane], r0);
  atomicAdd(&red[2 * lane + 1], r1);
  __syncthreads();
  int bb = (blockIdx.x * 4) >> 10;
  if (tid < 128) atomicAdd(&outacc[bb * kE + tid], red[tid]);
}

// ---------------- finalize ----------------
__global__ void fin_kernel(cfp outacc, const int* __restrict__ flag, void* __restrict__ out) {
  int i = blockIdx.x * 256 + threadIdx.x;
  float v = outacc[i] * (1.f / 1024.f);
  if (*flag) ((float*)out)[i] = v;
  else       ((bf16*)out)[i] = __float2bfloat16(v);
}

extern "C" void kernel_launch(void* const* d_in, const int* in_sizes, int n_in,
                              void* d_out, int out_size, void* d_ws, size_t ws_size,
                              hipStream_t stream) {
  CvtArgs args;
  int cum = 0;
  for (int i = 0; i < n_in && i < 27; ++i) {
    args.p[i] = d_in[i];
    args.cum[i] = cum;
    cum += in_sizes[i];
  }
  args.cum[n_in] = cum;
  int total = cum;
  int totalPad = (total + 15) & ~15;

  float* ws = (float*)d_ws;
  int* flag    = (int*)ws;
  float* wsinf = ws + 16;
  float* xsrc  = wsinf + totalPad;               // 2,097,152
  float* att   = xsrc + 2097152;                 // 2,097,152
  float* qkv0  = att + 2097152;                  // 3,145,728 (q,k,v bf16)
  float* ext   = qkv0 + 3145728;                 // 1,048,576 (ff1b tail)
  float* o     = ext + 1048576;                  // 2,097,152 (later yff)
  float* outacc = o + 2097152;                   // 2,048

  u16* qb = (u16*)qkv0;
  u16* kb = qb + 2097152;
  u16* vb = kb + 2097152;
  u16* ff1b = (u16*)qkv0;
  float* yff = o;

  const float* wf[27];
  for (int i = 0; i < n_in && i < 27; ++i) wf[i] = wsinf + args.cum[i];

  hipMemsetAsync(flag, 0, sizeof(int), stream);
  hipMemsetAsync(outacc, 0, 2048 * sizeof(float), stream);
  detect_kernel<<<(in_sizes[0] + 255) / 256, 256, 0, stream>>>(
      (const u16*)d_in[0], in_sizes[0], flag);
  convert_kernel<<<(total + 255) / 256, 256, 0, stream>>>(args, flag, wsinf, total);

  gemm_kernel<0, 0, 2048><<<dim3(128, 2), 256, 0, stream>>>(
      wf[0], wf[7], wf[1], wf[2], wf[3], wf[4], wf[5], wf[6],
      wf[8], wf[9], wf[10], wf[11], wf[12], xsrc, nullptr);
  gemm_kernel<2, 1, 128><<<dim3(128, 2), 256, 0, stream>>>(
      xsrc, wf[13], nullptr, nullptr, nullptr, nullptr, nullptr, nullptr,
      nullptr, nullptr, nullptr, nullptr, nullptr, qb, nullptr);
  gemm_kernel<2, 1, 128><<<dim3(128, 2), 256, 0, stream>>>(
      xsrc, wf[14], nullptr, nullptr, nullptr, nullptr, nullptr, nullptr,
      nullptr, nullptr, nullptr, nullptr, nullptr, kb, nullptr);
  gemm_kernel<2, 1, 128><<<dim3(128, 2), 256, 0, stream>>>(
      xsrc, wf[15], nullptr, nullptr, nullptr, nullptr, nullptr, nullptr,
      nullptr, nullptr, nullptr, nullptr, nullptr, vb, nullptr);

  attn_kernel<<<512, 512, 0, stream>>>(qb, kb, vb, wf[16], o);
  ln_kernel<<<4096, 256, 0, stream>>>(o, xsrc, wf[17], wf[18], wf[19], wf[20], att);

  gemm_kernel<1, 2, 128><<<dim3(128, 8), 256, 0, stream>>>(
      att, wf[21], wf[22], nullptr, nullptr, nullptr, nullptr, nullptr,
      nullptr, nullptr, nullptr, nullptr, nullptr, ff1b, nullptr);
  gemm_kernel<3, 3, 512><<<dim3(128, 2), 256, 0, stream>>>(
      ff1b, wf[23], wf[24], nullptr, nullptr, nullptr, nullptr, nullptr,
      nullptr, nullptr, nullptr, nullptr, nullptr, yff, att);

  ln2gap_kernel<<<4096, 256, 0, stream>>>(yff, wf[25], wf[26], outacc);
  fin_kernel<<<8, 256, 0, stream>>>(outacc, flag, d_out);
}

// Round 5
// 310.259 us; speedup vs baseline: 10.7293x; 1.1462x over previous
//
#include <hip/hip_runtime.h>
#include <hip/hip_bf16.h>
#include <math.h>

using bf16 = __hip_bfloat16;
typedef unsigned short u16;
typedef unsigned int u32;
typedef const float* __restrict__ cfp;

typedef __attribute__((ext_vector_type(8))) short short8v;
typedef __attribute__((ext_vector_type(4))) float f32x4;

static constexpr int kS = 1024, kE = 128, kH = 8, kDH = 16, kDFF = 512;
static constexpr float kEps = 1e-5f;

__device__ __forceinline__ float geluf(float x) { return 0.5f * x * (1.f + erff(x * 0.70710678118654752f)); }
__device__ __forceinline__ u16 f2b(float f) {
  u32 u = __float_as_uint(f);
  u32 r = (u + 0x7FFFu + ((u >> 16) & 1u)) >> 16;
  return (u16)r;
}

// ---------------- dtype detection (inputs bf16 vs f32) ----------------
__global__ void detect_kernel(const u16* __restrict__ xb, int n, int* __restrict__ flag) {
  int i = blockIdx.x * 256 + threadIdx.x;
  if (i >= n) return;
  int e = (xb[i] >> 7) & 0xFF;
  if (e >= 0xB5) *flag = 1;
}

struct CvtArgs { const void* p[27]; int cum[28]; };

__global__ void convert_kernel(CvtArgs a, const int* __restrict__ flag,
                               float* __restrict__ out, int total) {
  int idx = blockIdx.x * 256 + threadIdx.x;
  if (idx >= total) return;
  int id = 0;
  while (idx >= a.cum[id + 1]) ++id;
  int local = idx - a.cum[id];
  float v;
  if (*flag) v = ((const float*)a.p[id])[local];
  else       v = __bfloat162float(((const bf16*)a.p[id])[local]);
  out[idx] = v;
}

// ---------------- conv1+bn1+gelu -> Abuf bf16 [8192][2048] (one M-half) ----------------
// row = blockIdx.x (0..8191), thread tid handles c1 pair (2*tid, 2*tid+1), r=0..3.
__global__ __launch_bounds__(256) void convstage_kernel(
    cfp x, cfp w1, cfp c1b, cfp g1, cfp b1, cfp m1, cfp v1,
    u16* __restrict__ Abuf, int grow0) {
  __shared__ float xs[8][4];
  int row = blockIdx.x;
  int grow = grow0 + row;
  int b = grow >> 10, s = grow & 1023;
  int tid = threadIdx.x;
  if (tid < 8) {
    int gs = s - 3 + tid;
    float4 xv = (gs >= 0 && gs < kS) ? ((const float4*)x)[b * kS + gs]
                                     : make_float4(0.f, 0.f, 0.f, 0.f);
    xs[tid][0] = xv.x; xs[tid][1] = xv.y; xs[tid][2] = xv.z; xs[tid][3] = xv.w;
  }
  __syncthreads();
  short8v outv;
#pragma unroll
  for (int cc = 0; cc < 2; ++cc) {
    int cx = tid * 2 + cc;
    float w[8];
#pragma unroll
    for (int t = 0; t < 8; ++t) w[t] = w1[cx * 8 + t];
    float sc = g1[cx] * __frsqrt_rn(v1[cx] + kEps);
    float ofs = b1[cx] - m1[cx] * sc;
    float cb = c1b[cx];
#pragma unroll
    for (int r = 0; r < 4; ++r) {
      float h = cb;
#pragma unroll
      for (int t = 0; t < 8; ++t) h += xs[t][r] * w[t];
      outv[cc * 4 + r] = (short)f2b(geluf(h * sc + ofs));
    }
  }
  *(short8v*)(Abuf + (size_t)row * 2048 + tid * 8) = outv;
}

// =====================================================================
// bf16 MFMA GEMM: C[M,N] = A[M,K] * W[N,K]^T (+ fused epilogues)
// BM x 64 tile, BK=64; 4 waves (2x2), wave tile (BM/2) x 32.
// ASRC: 1 = f32 row-major A;  3 = bf16 row-major A
// MODE: 0 conv epi (+c2b,bn2,gelu -> xsrc f32; +PE -> xpeb bf16)
//       1 qkv epi  (z-selected W, scatter [b,h,s,d] bf16)
//       2 ff1 epi  (relu(+b1) -> bf16)
//       3 ff2 epi  (+b2 + residual -> f32)
// =====================================================================
template<int ASRC, int MODE, int KTOT, int BM>
__global__ __launch_bounds__(256, 4) void gemm_kernel(
    const void* __restrict__ Ap, cfp Wf,
    cfp p0, cfp p1, cfp p2, cfp p3, cfp p4, cfp p5,
    cfp p6, cfp p7, cfp p8, cfp p9, cfp p10,
    void* __restrict__ Out, void* __restrict__ Out2, cfp res, int mbase) {
  constexpr int MI = BM / 32;          // 16-row fragments per wave
  __shared__ short8v Ab[BM * 8];       // BM x 64 bf16, XOR-swizzled
  __shared__ short8v Bb[512];          // 64 x 64 bf16, XOR-swizzled

  int tid = threadIdx.x;
  int mtile = blockIdx.x, ntile = blockIdx.y;

  cfp Wsel = Wf;
  if (MODE == 1) Wsel = (blockIdx.z == 0) ? Wf : ((blockIdx.z == 1) ? p1 : p2);

  int wid = tid >> 6, lane = tid & 63;
  int m0w = (wid >> 1) * (BM / 2), n0w = (wid & 1) * 32;
  int lrow = lane & 15, lk = lane >> 4;

  f32x4 acc[MI][2];
#pragma unroll
  for (int mi = 0; mi < MI; ++mi)
#pragma unroll
    for (int ni = 0; ni < 2; ++ni) acc[mi][ni] = (f32x4){0.f, 0.f, 0.f, 0.f};

  for (int k0 = 0; k0 < KTOT; k0 += 64) {
    __syncthreads();
    // ---- stage A tile (BM x 64) ----
#pragma unroll
    for (int c = 0; c < BM / 32; ++c) {
      int chunk = tid + 256 * c;
      int row = chunk >> 3, kc = chunk & 7;
      int arow = mtile * BM + row;
      u32 off = ((u32)(row * 128 + kc * 16)) ^ ((u32)((row & 7) << 4));
      if (ASRC == 3) {
        const u16* As = (const u16*)Ap + (size_t)arow * KTOT + k0 + kc * 8;
        Ab[off >> 4] = *(const short8v*)As;
      } else {
        const float* Af = (const float*)Ap + (size_t)arow * KTOT + k0 + kc * 8;
        float4 xa = *(const float4*)Af;
        float4 xb = *(const float4*)(Af + 4);
        short8v sv;
        sv[0] = (short)f2b(xa.x); sv[1] = (short)f2b(xa.y);
        sv[2] = (short)f2b(xa.z); sv[3] = (short)f2b(xa.w);
        sv[4] = (short)f2b(xb.x); sv[5] = (short)f2b(xb.y);
        sv[6] = (short)f2b(xb.z); sv[7] = (short)f2b(xb.w);
        Ab[off >> 4] = sv;
      }
    }
    // ---- stage B tile (64 x 64) from f32 weights ----
#pragma unroll
    for (int c = 0; c < 2; ++c) {
      int chunk = tid + 256 * c;
      int row = chunk >> 3, kc = chunk & 7;
      const float* Wp = Wsel + (size_t)(ntile * 64 + row) * KTOT + k0 + kc * 8;
      float4 xa = *(const float4*)Wp;
      float4 xb = *(const float4*)(Wp + 4);
      short8v sv;
      sv[0] = (short)f2b(xa.x); sv[1] = (short)f2b(xa.y);
      sv[2] = (short)f2b(xa.z); sv[3] = (short)f2b(xa.w);
      sv[4] = (short)f2b(xb.x); sv[5] = (short)f2b(xb.y);
      sv[6] = (short)f2b(xb.z); sv[7] = (short)f2b(xb.w);
      u32 off = ((u32)(row * 128 + kc * 16)) ^ ((u32)((row & 7) << 4));
      Bb[off >> 4] = sv;
    }
    __syncthreads();
    // ---- MFMA ----
#pragma unroll
    for (int ks = 0; ks < 2; ++ks) {
      short8v af[MI], bfr[2];
#pragma unroll
      for (int mi = 0; mi < MI; ++mi) {
        int row = m0w + mi * 16 + lrow;
        u32 off = ((u32)(row * 128 + ks * 64 + lk * 16)) ^ ((u32)((row & 7) << 4));
        af[mi] = Ab[off >> 4];
      }
#pragma unroll
      for (int ni = 0; ni < 2; ++ni) {
        int row = n0w + ni * 16 + lrow;
        u32 off = ((u32)(row * 128 + ks * 64 + lk * 16)) ^ ((u32)((row & 7) << 4));
        bfr[ni] = Bb[off >> 4];
      }
#pragma unroll
      for (int mi = 0; mi < MI; ++mi)
#pragma unroll
        for (int ni = 0; ni < 2; ++ni)
          acc[mi][ni] = __builtin_amdgcn_mfma_f32_16x16x32_bf16(af[mi], bfr[ni], acc[mi][ni], 0, 0, 0);
    }
  }

  // ---- epilogue ----
#pragma unroll
  for (int ni = 0; ni < 2; ++ni) {
    int n = ntile * 64 + n0w + ni * 16 + lrow;
    float c0 = 0.f, c1v = 0.f, c2v = 0.f, div = 0.f;
    if (MODE == 0) {
      float scn = p7[n] * __frsqrt_rn(p10[n] + kEps);
      c1v = scn;
      c2v = (p6[n] - p9[n]) * scn + p8[n];
      div = __expf((float)(n >> 1) * (-0.14391156824963732f)) * 0.125f;
    } else if (MODE == 2 || MODE == 3) {
      c0 = p0[n];
    }
#pragma unroll
    for (int mi = 0; mi < MI; ++mi) {
#pragma unroll
      for (int r = 0; r < 4; ++r) {
        int grow = mbase + mtile * BM + m0w + mi * 16 + lk * 4 + r;
        float val = acc[mi][ni][r];
        if (MODE == 0) {
          float gv = geluf(val * c1v + c2v);
          ((float*)Out)[(size_t)grow * kE + n] = gv;
          int s = grow & 1023;
          float ang = (float)s * div;
          float pe = (n & 1) ? __cosf(ang) : __sinf(ang);
          ((u16*)Out2)[(size_t)grow * kE + n] = f2b(gv + pe);
        } else if (MODE == 1) {
          int s = grow & 1023, b_ = grow >> 10;
          u16* ob = (u16*)Out + (size_t)blockIdx.z * 2097152;
          ob[(((size_t)(b_ * kH + (n >> 4))) * kS + s) * kDH + (n & 15)] = f2b(val);
        } else if (MODE == 2) {
          ((u16*)Out)[(size_t)grow * kDFF + n] = f2b(fmaxf(val + c0, 0.f));
        } else {
          ((float*)Out)[(size_t)grow * kE + n] = val + c0 + res[(size_t)grow * kE + n];
        }
      }
    }
  }
}

// =====================================================================
// MFMA attention (unchanged from round 4 — passed)
// =====================================================================
__global__ __launch_bounds__(512, 4) void attn_kernel(
    const u16* __restrict__ qb, const u16* __restrict__ kb,
    const u16* __restrict__ vb, cfp relb, float* __restrict__ o) {
  __shared__ u16 Ksh[1024 * 16];
  __shared__ u16 Vsh[16 * 1032];
  __shared__ u16 rbf[2048];
  __shared__ u16 Pt[8][640];

  int tid = threadIdx.x;
  int quarter = blockIdx.x & 3;
  int h = (blockIdx.x >> 2) & 7;
  int bb = blockIdx.x >> 5;
  size_t base = (size_t)(bb * kH + h) * (kS * kDH);

  for (int j = tid; j < 1024; j += 512) {
    const uint4* src = (const uint4*)(kb + base + j * 16);
    ((uint4*)Ksh)[j * 2] = src[0];
    ((uint4*)Ksh)[j * 2 + 1] = src[1];
  }
  for (int j = tid; j < 1024; j += 512) {
    const uint4* src = (const uint4*)(vb + base + j * 16);
    uint4 a = src[0], b = src[1];
    u32 wv[8] = {a.x, a.y, a.z, a.w, b.x, b.y, b.z, b.w};
#pragma unroll
    for (int p = 0; p < 8; ++p) {
      Vsh[(2 * p) * 1032 + j]     = (u16)(wv[p] & 0xFFFFu);
      Vsh[(2 * p + 1) * 1032 + j] = (u16)(wv[p] >> 16);
    }
  }
  for (int t = tid; t < 2047; t += 512) rbf[t] = f2b(relb[t * kH + h]);
  if (tid == 0) rbf[2047] = 0;
  __syncthreads();

  int w = tid >> 6, l = tid & 63;
  int lr = l & 15, lg = l >> 4;
  u16* P = Pt[w];
  int qbase = quarter * 256 + w * 32;
  const float kScaleLn = 0.088388347648318447f;

  for (int qt = 0; qt < 2; ++qt) {
    int q0 = qbase + qt * 16;
    short8v qf = (short8v){0, 0, 0, 0, 0, 0, 0, 0};
    if (lg < 2)
      qf = *(const short8v*)(qb + base + (size_t)(q0 + lr) * 16 + lg * 8);
    f32x4 acc_e = (f32x4){0.f, 0.f, 0.f, 0.f};
    f32x4 acc_rb = (f32x4){0.f, 0.f, 0.f, 0.f};
    float lac[4] = {0.f, 0.f, 0.f, 0.f};

    for (int jb = 0; jb < 32; ++jb) {
#pragma unroll
      for (int hh = 0; hh < 2; ++hh) {
        int kb16 = jb * 2 + hh;
        short8v kf = (short8v){0, 0, 0, 0, 0, 0, 0, 0};
        if (lg < 2)
          kf = *(const short8v*)(Ksh + (kb16 * 16 + lr) * 16 + lg * 8);
        f32x4 s = __builtin_amdgcn_mfma_f32_16x16x32_bf16(
            qf, kf, (f32x4){0.f, 0.f, 0.f, 0.f}, 0, 0, 0);
        int colb = hh * 16 + lr;
#pragma unroll
        for (int r = 0; r < 4; ++r) {
          float e = __expf(s[r] * kScaleLn);
          lac[r] += e;
          P[(lg * 4 + r) * 40 + colb] = f2b(e);
        }
      }
      short8v pf = *(const short8v*)(P + lr * 40 + lg * 8);
      short8v vf = *(const short8v*)(Vsh + lr * 1032 + jb * 32 + lg * 8);
      acc_e = __builtin_amdgcn_mfma_f32_16x16x32_bf16(pf, vf, acc_e, 0, 0, 0);
      int t0 = q0 + lr - jb * 32 - lg * 8 + 1023;
      short8v rf;
#pragma unroll
      for (int e = 0; e < 8; ++e) rf[e] = (short)rbf[t0 - e];
      acc_rb = __builtin_amdgcn_mfma_f32_16x16x32_bf16(rf, vf, acc_rb, 0, 0, 0);
    }

#pragma unroll
    for (int r = 0; r < 4; ++r) {
      lac[r] += __shfl_xor(lac[r], 1);
      lac[r] += __shfl_xor(lac[r], 2);
      lac[r] += __shfl_xor(lac[r], 4);
      lac[r] += __shfl_xor(lac[r], 8);
    }
#pragma unroll
    for (int r = 0; r < 4; ++r) {
      float inv = 1.f / lac[r];
      int row = q0 + lg * 4 + r;
      o[(size_t)(bb * kS + row) * kE + h * kDH + lr] = acc_e[r] * inv + acc_rb[r];
    }
  }
}

// ---------------- LN(attn out) + residual + LN1 -> att ----------------
__global__ __launch_bounds__(256) void ln_kernel(
    cfp o, cfp xsrc, cfp lag, cfp lab, cfp l1g, cfp l1b, float* __restrict__ att) {
  int row = blockIdx.x * 4 + (threadIdx.x >> 6);
  int lane = threadIdx.x & 63;
  float2 a = ((const float2*)(o + (size_t)row * kE))[lane];
  float sum = a.x + a.y;
  for (int off = 1; off < 64; off <<= 1) sum += __shfl_xor(sum, off);
  float mean = sum * (1.f / 128.f);
  float d0 = a.x - mean, d1 = a.y - mean;
  float ss = d0 * d0 + d1 * d1;
  for (int off = 1; off < 64; off <<= 1) ss += __shfl_xor(ss, off);
  float inv = 1.f / sqrtf(ss * (1.f / 128.f) + kEps);
  float t0 = d0 * inv * lag[2 * lane] + lab[2 * lane];
  float t1 = d1 * inv * lag[2 * lane + 1] + lab[2 * lane + 1];
  float2 xv = ((const float2*)(xsrc + (size_t)row * kE))[lane];
  t0 += xv.x; t1 += xv.y;
  float sum2 = t0 + t1;
  for (int off = 1; off < 64; off <<= 1) sum2 += __shfl_xor(sum2, off);
  float mean2 = sum2 * (1.f / 128.f);
  float e0 = t0 - mean2, e1 = t1 - mean2;
  float ss2 = e0 * e0 + e1 * e1;
  for (int off = 1; off < 64; off <<= 1) ss2 += __shfl_xor(ss2, off);
  float inv2 = 1.f / sqrtf(ss2 * (1.f / 128.f) + kEps);
  float r0 = e0 * inv2 * l1g[2 * lane] + l1b[2 * lane];
  float r1 = e1 * inv2 * l1g[2 * lane + 1] + l1b[2 * lane + 1];
  ((float2*)(att + (size_t)row * kE))[lane] = make_float2(r0, r1);
}

// ---------------- LN2 + GAP ----------------
__global__ __launch_bounds__(256) void ln2gap_kernel(
    cfp yff, cfp l2g, cfp l2b, float* __restrict__ outacc) {
  __shared__ float red[128];
  int tid = threadIdx.x;
  if (tid < 128) red[tid] = 0.f;
  __syncthreads();
  int row = blockIdx.x * 4 + (tid >> 6);
  int lane = tid & 63;
  float2 a = ((const float2*)(yff + (size_t)row * kE))[lane];
  float sum = a.x + a.y;
  for (int off = 1; off < 64; off <<= 1) sum += __shfl_xor(sum, off);
  float mean = sum * (1.f / 128.f);
  float d0 = a.x - mean, d1 = a.y - mean;
  float ss = d0 * d0 + d1 * d1;
  for (int off = 1; off < 64; off <<= 1) ss += __shfl_xor(ss, off);
  float inv = 1.f / sqrtf(ss * (1.f / 128.f) + kEps);
  float r0 = d0 * inv * l2g[2 * lane] + l2b[2 * lane];
  float r1 = d1 * inv * l2g[2 * lane + 1] + l2b[2 * lane + 1];
  atomicAdd(&red[2 * lane], r0);
  atomicAdd(&red[2 * lane + 1], r1);
  __syncthreads();
  int bb = (blockIdx.x * 4) >> 10;
  if (tid < 128) atomicAdd(&outacc[bb * kE + tid], red[tid]);
}

// ---------------- finalize ----------------
__global__ void fin_kernel(cfp outacc, const int* __restrict__ flag, void* __restrict__ out) {
  int i = blockIdx.x * 256 + threadIdx.x;
  float v = outacc[i] * (1.f / 1024.f);
  if (*flag) ((float*)out)[i] = v;
  else       ((bf16*)out)[i] = __float2bfloat16(v);
}

extern "C" void kernel_launch(void* const* d_in, const int* in_sizes, int n_in,
                              void* d_out, int out_size, void* d_ws, size_t ws_size,
                              hipStream_t stream) {
  CvtArgs args;
  int cum = 0;
  for (int i = 0; i < n_in && i < 27; ++i) {
    args.p[i] = d_in[i];
    args.cum[i] = cum;
    cum += in_sizes[i];
  }
  args.cum[n_in] = cum;
  int total = cum;
  int totalPad = (total + 15) & ~15;

  float* ws = (float*)d_ws;
  int* flag    = (int*)ws;
  float* wsinf = ws + 16;
  float* xsrc  = wsinf + totalPad;               // 2,097,152 f32
  float* att   = xsrc + 2097152;                 // 2,097,152 f32
  float* qkv0  = att + 2097152;                  // 3,145,728 (q,k,v bf16)
  float* ext   = qkv0 + 3145728;                 // 1,048,576 (ff1b tail)
  float* o     = ext + 1048576;                  // 2,097,152 (later yff)
  float* outacc = o + 2097152;                   // 2,048
  u16* xpeb    = (u16*)(outacc + 2048);          // 2,097,152 u16 (4 MB)

  u16* Abuf = (u16*)att;                         // overlays att..o (33.55 MB), dead at conv time
  u16* qb = (u16*)qkv0;
  u16* kb = qb + 2097152;
  u16* vb = kb + 2097152;
  u16* ff1b = (u16*)qkv0;
  float* yff = o;

  const float* wf[27];
  for (int i = 0; i < n_in && i < 27; ++i) wf[i] = wsinf + args.cum[i];

  hipMemsetAsync(flag, 0, sizeof(int), stream);
  hipMemsetAsync(outacc, 0, 2048 * sizeof(float), stream);
  detect_kernel<<<(in_sizes[0] + 255) / 256, 256, 0, stream>>>(
      (const u16*)d_in[0], in_sizes[0], flag);
  convert_kernel<<<(total + 255) / 256, 256, 0, stream>>>(args, flag, wsinf, total);

  // conv1+bn1+gelu staged to bf16, then clean MFMA GEMM; two M-halves share Abuf
  for (int hm = 0; hm < 2; ++hm) {
    convstage_kernel<<<8192, 256, 0, stream>>>(
        wf[0], wf[1], wf[2], wf[3], wf[4], wf[5], wf[6], Abuf, hm * 8192);
    gemm_kernel<3, 0, 2048, 64><<<dim3(128, 2), 256, 0, stream>>>(
        Abuf, wf[7], nullptr, nullptr, nullptr, nullptr, nullptr, nullptr,
        wf[8], wf[9], wf[10], wf[11], wf[12], xsrc, xpeb, nullptr, hm * 8192);
  }

  // QKV: one launch, z selects W and output slot
  gemm_kernel<3, 1, 128, 128><<<dim3(128, 2, 3), 256, 0, stream>>>(
      xpeb, wf[13], nullptr, wf[14], wf[15], nullptr, nullptr, nullptr,
      nullptr, nullptr, nullptr, nullptr, nullptr, qb, nullptr, nullptr, 0);

  attn_kernel<<<512, 512, 0, stream>>>(qb, kb, vb, wf[16], o);
  ln_kernel<<<4096, 256, 0, stream>>>(o, xsrc, wf[17], wf[18], wf[19], wf[20], att);

  gemm_kernel<1, 2, 128, 128><<<dim3(128, 8), 256, 0, stream>>>(
      att, wf[21], wf[22], nullptr, nullptr, nullptr, nullptr, nullptr,
      nullptr, nullptr, nullptr, nullptr, nullptr, ff1b, nullptr, nullptr, 0);
  gemm_kernel<3, 3, 512, 128><<<dim3(128, 2), 256, 0, stream>>>(
      ff1b, wf[23], wf[24], nullptr, nullptr, nullptr, nullptr, nullptr,
      nullptr, nullptr, nullptr, nullptr, nullptr, yff, nullptr, att, 0);

  ln2gap_kernel<<<4096, 256, 0, stream>>>(yff, wf[25], wf[26], outacc);
  fin_kernel<<<8, 256, 0, stream>>>(outacc, flag, d_out);
}

// Round 6
// 292.618 us; speedup vs baseline: 11.3761x; 1.0603x over previous
//
#include <hip/hip_runtime.h>
#include <hip/hip_bf16.h>
#include <math.h>

using bf16 = __hip_bfloat16;
typedef unsigned short u16;
typedef unsigned int u32;
typedef const float* __restrict__ cfp;

typedef __attribute__((ext_vector_type(8))) short short8v;
typedef __attribute__((ext_vector_type(4))) float f32x4;

static constexpr int kS = 1024, kE = 128, kH = 8, kDH = 16, kDFF = 512;
static constexpr float kEps = 1e-5f;

__device__ __forceinline__ float geluf(float x) { return 0.5f * x * (1.f + erff(x * 0.70710678118654752f)); }
__device__ __forceinline__ u16 f2b(float f) {
  u32 u = __float_as_uint(f);
  u32 r = (u + 0x7FFFu + ((u >> 16) & 1u)) >> 16;
  return (u16)r;
}

// ---------------- dtype detection (inputs bf16 vs f32) ----------------
__global__ void detect_kernel(const u16* __restrict__ xb, int n, int* __restrict__ flag) {
  int i = blockIdx.x * 256 + threadIdx.x;
  if (i >= n) return;
  int e = (xb[i] >> 7) & 0xFF;
  if (e >= 0xB5) *flag = 1;
}

struct CvtArgs { const void* p[27]; int cum[28]; };

__global__ void convert_kernel(CvtArgs a, const int* __restrict__ flag,
                               float* __restrict__ out, int total) {
  int idx = blockIdx.x * 256 + threadIdx.x;
  if (idx >= total) return;
  int id = 0;
  while (idx >= a.cum[id + 1]) ++id;
  int local = idx - a.cum[id];
  float v;
  if (*flag) v = ((const float*)a.p[id])[local];
  else       v = __bfloat162float(((const bf16*)a.p[id])[local]);
  out[idx] = v;
}

// ---------------- conv1+bn1+gelu -> Abuf bf16 [8192][2048] (one M-half) ----------------
__global__ __launch_bounds__(256) void convstage_kernel(
    cfp x, cfp w1, cfp c1b, cfp g1, cfp b1, cfp m1, cfp v1,
    u16* __restrict__ Abuf, int grow0) {
  __shared__ float xs[8][4];
  int row = blockIdx.x;
  int grow = grow0 + row;
  int b = grow >> 10, s = grow & 1023;
  int tid = threadIdx.x;
  if (tid < 8) {
    int gs = s - 3 + tid;
    float4 xv = (gs >= 0 && gs < kS) ? ((const float4*)x)[b * kS + gs]
                                     : make_float4(0.f, 0.f, 0.f, 0.f);
    xs[tid][0] = xv.x; xs[tid][1] = xv.y; xs[tid][2] = xv.z; xs[tid][3] = xv.w;
  }
  __syncthreads();
  short8v outv;
#pragma unroll
  for (int cc = 0; cc < 2; ++cc) {
    int cx = tid * 2 + cc;
    float w[8];
#pragma unroll
    for (int t = 0; t < 8; ++t) w[t] = w1[cx * 8 + t];
    float sc = g1[cx] * __frsqrt_rn(v1[cx] + kEps);
    float ofs = b1[cx] - m1[cx] * sc;
    float cb = c1b[cx];
#pragma unroll
    for (int r = 0; r < 4; ++r) {
      float h = cb;
#pragma unroll
      for (int t = 0; t < 8; ++t) h += xs[t][r] * w[t];
      outv[cc * 4 + r] = (short)f2b(geluf(h * sc + ofs));
    }
  }
  *(short8v*)(Abuf + (size_t)row * 2048 + tid * 8) = outv;
}

// ---------------- rel-bias MFMA fragment table ----------------
// T[h][t][lane][e] = bf16(rb_h[16t + 31 + (l&15) - 8*(l>>4) - e]), t in [0,126)
__global__ __launch_bounds__(64) void rbtab_kernel(cfp relb, u16* __restrict__ T) {
  int t = blockIdx.x, h = blockIdx.y;
  int l = threadIdx.x;
  int lr = l & 15, lg = l >> 4;
  short8v v;
#pragma unroll
  for (int e = 0; e < 8; ++e) {
    int idx = 16 * t + 31 + lr - 8 * lg - e;
    v[e] = (short)f2b(relb[idx * 8 + h]);
  }
  *(short8v*)(T + ((size_t)(h * 126 + t) * 64 + l) * 8) = v;
}

// =====================================================================
// bf16 MFMA GEMM (unchanged structure — proven)
// =====================================================================
template<int ASRC, int MODE, int KTOT, int BM>
__global__ __launch_bounds__(256, 4) void gemm_kernel(
    const void* __restrict__ Ap, cfp Wf,
    cfp p0, cfp p1, cfp p2, cfp p3, cfp p4, cfp p5,
    cfp p6, cfp p7, cfp p8, cfp p9, cfp p10,
    void* __restrict__ Out, void* __restrict__ Out2, cfp res, int mbase) {
  constexpr int MI = BM / 32;
  __shared__ short8v Ab[BM * 8];
  __shared__ short8v Bb[512];

  int tid = threadIdx.x;
  int mtile = blockIdx.x, ntile = blockIdx.y;

  cfp Wsel = Wf;
  if (MODE == 1) Wsel = (blockIdx.z == 0) ? Wf : ((blockIdx.z == 1) ? p1 : p2);

  int wid = tid >> 6, lane = tid & 63;
  int m0w = (wid >> 1) * (BM / 2), n0w = (wid & 1) * 32;
  int lrow = lane & 15, lk = lane >> 4;

  f32x4 acc[MI][2];
#pragma unroll
  for (int mi = 0; mi < MI; ++mi)
#pragma unroll
    for (int ni = 0; ni < 2; ++ni) acc[mi][ni] = (f32x4){0.f, 0.f, 0.f, 0.f};

  for (int k0 = 0; k0 < KTOT; k0 += 64) {
    __syncthreads();
#pragma unroll
    for (int c = 0; c < BM / 32; ++c) {
      int chunk = tid + 256 * c;
      int row = chunk >> 3, kc = chunk & 7;
      int arow = mtile * BM + row;
      u32 off = ((u32)(row * 128 + kc * 16)) ^ ((u32)((row & 7) << 4));
      if (ASRC == 3) {
        const u16* As = (const u16*)Ap + (size_t)arow * KTOT + k0 + kc * 8;
        Ab[off >> 4] = *(const short8v*)As;
      } else {
        const float* Af = (const float*)Ap + (size_t)arow * KTOT + k0 + kc * 8;
        float4 xa = *(const float4*)Af;
        float4 xb = *(const float4*)(Af + 4);
        short8v sv;
        sv[0] = (short)f2b(xa.x); sv[1] = (short)f2b(xa.y);
        sv[2] = (short)f2b(xa.z); sv[3] = (short)f2b(xa.w);
        sv[4] = (short)f2b(xb.x); sv[5] = (short)f2b(xb.y);
        sv[6] = (short)f2b(xb.z); sv[7] = (short)f2b(xb.w);
        Ab[off >> 4] = sv;
      }
    }
#pragma unroll
    for (int c = 0; c < 2; ++c) {
      int chunk = tid + 256 * c;
      int row = chunk >> 3, kc = chunk & 7;
      const float* Wp = Wsel + (size_t)(ntile * 64 + row) * KTOT + k0 + kc * 8;
      float4 xa = *(const float4*)Wp;
      float4 xb = *(const float4*)(Wp + 4);
      short8v sv;
      sv[0] = (short)f2b(xa.x); sv[1] = (short)f2b(xa.y);
      sv[2] = (short)f2b(xa.z); sv[3] = (short)f2b(xa.w);
      sv[4] = (short)f2b(xb.x); sv[5] = (short)f2b(xb.y);
      sv[6] = (short)f2b(xb.z); sv[7] = (short)f2b(xb.w);
      u32 off = ((u32)(row * 128 + kc * 16)) ^ ((u32)((row & 7) << 4));
      Bb[off >> 4] = sv;
    }
    __syncthreads();
#pragma unroll
    for (int ks = 0; ks < 2; ++ks) {
      short8v af[MI], bfr[2];
#pragma unroll
      for (int mi = 0; mi < MI; ++mi) {
        int row = m0w + mi * 16 + lrow;
        u32 off = ((u32)(row * 128 + ks * 64 + lk * 16)) ^ ((u32)((row & 7) << 4));
        af[mi] = Ab[off >> 4];
      }
#pragma unroll
      for (int ni = 0; ni < 2; ++ni) {
        int row = n0w + ni * 16 + lrow;
        u32 off = ((u32)(row * 128 + ks * 64 + lk * 16)) ^ ((u32)((row & 7) << 4));
        bfr[ni] = Bb[off >> 4];
      }
#pragma unroll
      for (int mi = 0; mi < MI; ++mi)
#pragma unroll
        for (int ni = 0; ni < 2; ++ni)
          acc[mi][ni] = __builtin_amdgcn_mfma_f32_16x16x32_bf16(af[mi], bfr[ni], acc[mi][ni], 0, 0, 0);
    }
  }

#pragma unroll
  for (int ni = 0; ni < 2; ++ni) {
    int n = ntile * 64 + n0w + ni * 16 + lrow;
    float c0 = 0.f, c1v = 0.f, c2v = 0.f, div = 0.f;
    if (MODE == 0) {
      float scn = p7[n] * __frsqrt_rn(p10[n] + kEps);
      c1v = scn;
      c2v = (p6[n] - p9[n]) * scn + p8[n];
      div = __expf((float)(n >> 1) * (-0.14391156824963732f)) * 0.125f;
    } else if (MODE == 2 || MODE == 3) {
      c0 = p0[n];
    }
#pragma unroll
    for (int mi = 0; mi < MI; ++mi) {
#pragma unroll
      for (int r = 0; r < 4; ++r) {
        int grow = mbase + mtile * BM + m0w + mi * 16 + lk * 4 + r;
        float val = acc[mi][ni][r];
        if (MODE == 0) {
          float gv = geluf(val * c1v + c2v);
          ((float*)Out)[(size_t)grow * kE + n] = gv;
          int s = grow & 1023;
          float ang = (float)s * div;
          float pe = (n & 1) ? __cosf(ang) : __sinf(ang);
          ((u16*)Out2)[(size_t)grow * kE + n] = f2b(gv + pe);
        } else if (MODE == 1) {
          int s = grow & 1023, b_ = grow >> 10;
          u16* ob = (u16*)Out + (size_t)blockIdx.z * 2097152;
          ob[(((size_t)(b_ * kH + (n >> 4))) * kS + s) * kDH + (n & 15)] = f2b(val);
        } else if (MODE == 2) {
          ((u16*)Out)[(size_t)grow * kDFF + n] = f2b(fmaxf(val + c0, 0.f));
        } else {
          ((float*)Out)[(size_t)grow * kE + n] = val + c0 + res[(size_t)grow * kE + n];
        }
      }
    }
  }
}

// =====================================================================
// MFMA attention v2: swapped QK (lane holds k-contiguous scores per q),
// K/rb fragments from global (L2), V transposed in LDS, per-wave P tile.
// =====================================================================
__global__ __launch_bounds__(512, 4) void attn_kernel(
    const u16* __restrict__ qb, const u16* __restrict__ kb,
    const u16* __restrict__ vb, const u16* __restrict__ rbT,
    float* __restrict__ o) {
  __shared__ u16 Vsh[16 * 1032];   // V^T [d][j], stride 1032
  __shared__ u16 Pt[8][1280];      // per-wave P [32 q][40 k]

  int tid = threadIdx.x;
  int quarter = blockIdx.x & 3;
  int h = (blockIdx.x >> 2) & 7;
  int bb = blockIdx.x >> 5;
  size_t base = (size_t)(bb * kH + h) * (kS * kDH);

  for (int j = tid; j < 1024; j += 512) {
    const uint4* src = (const uint4*)(vb + base + j * 16);
    uint4 a = src[0], b = src[1];
    u32 wv[8] = {a.x, a.y, a.z, a.w, b.x, b.y, b.z, b.w};
#pragma unroll
    for (int p = 0; p < 8; ++p) {
      Vsh[(2 * p) * 1032 + j]     = (u16)(wv[p] & 0xFFFFu);
      Vsh[(2 * p + 1) * 1032 + j] = (u16)(wv[p] >> 16);
    }
  }
  __syncthreads();

  int w = tid >> 6, l = tid & 63;
  int lr = l & 15, lg = l >> 4;
  u16* P = Pt[w];
  int q0w = quarter * 256 + w * 32;
  int tbase = (q0w + 992) >> 4;
  const float cs = 0.088388347648318447f;   // 128^-0.5
  const u16* rbh = rbT + (size_t)h * 126 * 512;

  short8v qf[2];
#pragma unroll
  for (int qt = 0; qt < 2; ++qt) {
    qf[qt] = (short8v){0, 0, 0, 0, 0, 0, 0, 0};
    if (lg < 2)
      qf[qt] = *(const short8v*)(qb + base + (size_t)(q0w + qt * 16 + lr) * 16 + lg * 8);
  }
  f32x4 acc_e[2], acc_rb[2];
  float lac[2] = {0.f, 0.f};
#pragma unroll
  for (int qt = 0; qt < 2; ++qt) {
    acc_e[qt] = (f32x4){0.f, 0.f, 0.f, 0.f};
    acc_rb[qt] = (f32x4){0.f, 0.f, 0.f, 0.f};
  }

  for (int jb = 0; jb < 32; ++jb) {
    short8v kf0 = (short8v){0, 0, 0, 0, 0, 0, 0, 0};
    short8v kf1 = (short8v){0, 0, 0, 0, 0, 0, 0, 0};
    if (lg < 2) {
      kf0 = *(const short8v*)(kb + base + (size_t)(jb * 32 + lr) * 16 + lg * 8);
      kf1 = *(const short8v*)(kb + base + (size_t)(jb * 32 + 16 + lr) * 16 + lg * 8);
    }
    short8v vf = *(const short8v*)(Vsh + lr * 1032 + jb * 32 + lg * 8);
#pragma unroll
    for (int qt = 0; qt < 2; ++qt) {
      // S^T tiles: lane holds q = lr, k = hh*16 + 4*lg + r
      f32x4 s0 = __builtin_amdgcn_mfma_f32_16x16x32_bf16(kf0, qf[qt], (f32x4){0.f, 0.f, 0.f, 0.f}, 0, 0, 0);
      f32x4 s1 = __builtin_amdgcn_mfma_f32_16x16x32_bf16(kf1, qf[qt], (f32x4){0.f, 0.f, 0.f, 0.f}, 0, 0, 0);
      float e0 = __expf(s0[0] * cs), e1 = __expf(s0[1] * cs);
      float e2 = __expf(s0[2] * cs), e3 = __expf(s0[3] * cs);
      float f0 = __expf(s1[0] * cs), f1 = __expf(s1[1] * cs);
      float f2 = __expf(s1[2] * cs), f3 = __expf(s1[3] * cs);
      lac[qt] += (e0 + e1) + (e2 + e3) + (f0 + f1) + (f2 + f3);
      uint2 w0, w1;
      w0.x = (u32)f2b(e0) | ((u32)f2b(e1) << 16);
      w0.y = (u32)f2b(e2) | ((u32)f2b(e3) << 16);
      w1.x = (u32)f2b(f0) | ((u32)f2b(f1) << 16);
      w1.y = (u32)f2b(f2) | ((u32)f2b(f3) << 16);
      int prow = (qt * 16 + lr) * 40;
      *(uint2*)(P + prow + 4 * lg)      = w0;   // hh=0: k = 4lg..4lg+3
      *(uint2*)(P + prow + 16 + 4 * lg) = w1;   // hh=1
      // PV fragments: lane reads row q = qt*16 + lr, k = lg*8..+7
      short8v pf = *(const short8v*)(P + (qt * 16 + lr) * 40 + lg * 8);
      int t = tbase + qt - 2 * jb;
      short8v rf = *(const short8v*)(rbh + ((size_t)t * 64 + l) * 8);
      acc_e[qt]  = __builtin_amdgcn_mfma_f32_16x16x32_bf16(pf, vf, acc_e[qt], 0, 0, 0);
      acc_rb[qt] = __builtin_amdgcn_mfma_f32_16x16x32_bf16(rf, vf, acc_rb[qt], 0, 0, 0);
    }
  }

#pragma unroll
  for (int qt = 0; qt < 2; ++qt) {
    float ls = lac[qt];
    ls += __shfl_xor(ls, 16);
    ls += __shfl_xor(ls, 32);
#pragma unroll
    for (int r = 0; r < 4; ++r) {
      float lsq = __shfl(ls, lg * 4 + r);    // lane (lg*4+r) holds q=lg*4+r sum
      int row = q0w + qt * 16 + lg * 4 + r;
      o[(size_t)(bb * kS + row) * kE + h * kDH + lr] = acc_e[qt][r] / lsq + acc_rb[qt][r];
    }
  }
}

// ---------------- LN(attn out) + residual + LN1 -> att (f32 + bf16) ----------------
__global__ __launch_bounds__(256) void ln_kernel(
    cfp o, cfp xsrc, cfp lag, cfp lab, cfp l1g, cfp l1b,
    float* __restrict__ att, u16* __restrict__ attb) {
  int row = blockIdx.x * 4 + (threadIdx.x >> 6);
  int lane = threadIdx.x & 63;
  float2 a = ((const float2*)(o + (size_t)row * kE))[lane];
  float sum = a.x + a.y;
  for (int off = 1; off < 64; off <<= 1) sum += __shfl_xor(sum, off);
  float mean = sum * (1.f / 128.f);
  float d0 = a.x - mean, d1 = a.y - mean;
  float ss = d0 * d0 + d1 * d1;
  for (int off = 1; off < 64; off <<= 1) ss += __shfl_xor(ss, off);
  float inv = 1.f / sqrtf(ss * (1.f / 128.f) + kEps);
  float t0 = d0 * inv * lag[2 * lane] + lab[2 * lane];
  float t1 = d1 * inv * lag[2 * lane + 1] + lab[2 * lane + 1];
  float2 xv = ((const float2*)(xsrc + (size_t)row * kE))[lane];
  t0 += xv.x; t1 += xv.y;
  float sum2 = t0 + t1;
  for (int off = 1; off < 64; off <<= 1) sum2 += __shfl_xor(sum2, off);
  float mean2 = sum2 * (1.f / 128.f);
  float e0 = t0 - mean2, e1 = t1 - mean2;
  float ss2 = e0 * e0 + e1 * e1;
  for (int off = 1; off < 64; off <<= 1) ss2 += __shfl_xor(ss2, off);
  float inv2 = 1.f / sqrtf(ss2 * (1.f / 128.f) + kEps);
  float r0 = e0 * inv2 * l1g[2 * lane] + l1b[2 * lane];
  float r1 = e1 * inv2 * l1g[2 * lane + 1] + l1b[2 * lane + 1];
  ((float2*)(att + (size_t)row * kE))[lane] = make_float2(r0, r1);
  ((u32*)attb)[(size_t)row * 64 + lane] = (u32)f2b(r0) | ((u32)f2b(r1) << 16);
}

// ---------------- LN2 + GAP ----------------
__global__ __launch_bounds__(256) void ln2gap_kernel(
    cfp yff, cfp l2g, cfp l2b, float* __restrict__ outacc) {
  __shared__ float red[128];
  int tid = threadIdx.x;
  if (tid < 128) red[tid] = 0.f;
  __syncthreads();
  int row = blockIdx.x * 4 + (tid >> 6);
  int lane = tid & 63;
  float2 a = ((const float2*)(yff + (size_t)row * kE))[lane];
  float sum = a.x + a.y;
  for (int off = 1; off < 64; off <<= 1) sum += __shfl_xor(sum, off);
  float mean = sum * (1.f / 128.f);
  float d0 = a.x - mean, d1 = a.y - mean;
  float ss = d0 * d0 + d1 * d1;
  for (int off = 1; off < 64; off <<= 1) ss += __shfl_xor(ss, off);
  float inv = 1.f / sqrtf(ss * (1.f / 128.f) + kEps);
  float r0 = d0 * inv * l2g[2 * lane] + l2b[2 * lane];
  float r1 = d1 * inv * l2g[2 * lane + 1] + l2b[2 * lane + 1];
  atomicAdd(&red[2 * lane], r0);
  atomicAdd(&red[2 * lane + 1], r1);
  __syncthreads();
  int bb = (blockIdx.x * 4) >> 10;
  if (tid < 128) atomicAdd(&outacc[bb * kE + tid], red[tid]);
}

// ---------------- finalize ----------------
__global__ void fin_kernel(cfp outacc, const int* __restrict__ flag, void* __restrict__ out) {
  int i = blockIdx.x * 256 + threadIdx.x;
  float v = outacc[i] * (1.f / 1024.f);
  if (*flag) ((float*)out)[i] = v;
  else       ((bf16*)out)[i] = __float2bfloat16(v);
}

extern "C" void kernel_launch(void* const* d_in, const int* in_sizes, int n_in,
                              void* d_out, int out_size, void* d_ws, size_t ws_size,
                              hipStream_t stream) {
  CvtArgs args;
  int cum = 0;
  for (int i = 0; i < n_in && i < 27; ++i) {
    args.p[i] = d_in[i];
    args.cum[i] = cum;
    cum += in_sizes[i];
  }
  args.cum[n_in] = cum;
  int total = cum;
  int totalPad = (total + 15) & ~15;

  float* ws = (float*)d_ws;
  int* flag    = (int*)ws;
  float* wsinf = ws + 16;
  float* xsrc  = wsinf + totalPad;               // 2,097,152 f32
  float* att   = xsrc + 2097152;                 // 2,097,152 f32
  float* qkv0  = att + 2097152;                  // 3,145,728 (q,k,v bf16)
  float* ext   = qkv0 + 3145728;                 // 1,048,576 (rbT; ff1b tail)
  float* o     = ext + 1048576;                  // 2,097,152 (later yff)
  float* outacc = o + 2097152;                   // 2,048
  u16* xpeb    = (u16*)(outacc + 2048);          // 2,097,152 u16 (xsrc+PE bf16; later attb)

  u16* Abuf = (u16*)att;                         // overlays att..o (33.55 MB), dead at conv time
  u16* qb = (u16*)qkv0;
  u16* kb = qb + 2097152;
  u16* vb = kb + 2097152;
  u16* rbT = (u16*)ext;                          // 1 MB, written after conv, dead after attn
  u16* ff1b = (u16*)qkv0;                        // spans qkv0+ext (16.78 MB)
  u16* attb = xpeb;                              // reuse xpeb after qkv consumed it
  float* yff = o;

  const float* wf[27];
  for (int i = 0; i < n_in && i < 27; ++i) wf[i] = wsinf + args.cum[i];

  hipMemsetAsync(flag, 0, sizeof(int), stream);
  hipMemsetAsync(outacc, 0, 2048 * sizeof(float), stream);
  detect_kernel<<<(in_sizes[0] + 255) / 256, 256, 0, stream>>>(
      (const u16*)d_in[0], in_sizes[0], flag);
  convert_kernel<<<(total + 255) / 256, 256, 0, stream>>>(args, flag, wsinf, total);

  // conv1+bn1+gelu staged to bf16, then MFMA GEMM; two M-halves share Abuf
  for (int hm = 0; hm < 2; ++hm) {
    convstage_kernel<<<8192, 256, 0, stream>>>(
        wf[0], wf[1], wf[2], wf[3], wf[4], wf[5], wf[6], Abuf, hm * 8192);
    gemm_kernel<3, 0, 2048, 64><<<dim3(128, 2), 256, 0, stream>>>(
        Abuf, wf[7], nullptr, nullptr, nullptr, nullptr, nullptr, nullptr,
        wf[8], wf[9], wf[10], wf[11], wf[12], xsrc, xpeb, nullptr, hm * 8192);
  }

  // rel-bias fragment table (after Abuf is dead — rbT lives in ext)
  rbtab_kernel<<<dim3(126, 8), 64, 0, stream>>>(wf[16], rbT);

  // QKV: one launch, z selects W and output slot
  gemm_kernel<3, 1, 128, 128><<<dim3(128, 2, 3), 256, 0, stream>>>(
      xpeb, wf[13], nullptr, wf[14], wf[15], nullptr, nullptr, nullptr,
      nullptr, nullptr, nullptr, nullptr, nullptr, qb, nullptr, nullptr, 0);

  attn_kernel<<<512, 512, 0, stream>>>(qb, kb, vb, rbT, o);
  ln_kernel<<<4096, 256, 0, stream>>>(o, xsrc, wf[17], wf[18], wf[19], wf[20], att, attb);

  gemm_kernel<3, 2, 128, 128><<<dim3(128, 8), 256, 0, stream>>>(
      attb, wf[21], wf[22], nullptr, nullptr, nullptr, nullptr, nullptr,
      nullptr, nullptr, nullptr, nullptr, nullptr, ff1b, nullptr, nullptr, 0);
  gemm_kernel<3, 3, 512, 128><<<dim3(128, 2), 256, 0, stream>>>(
      ff1b, wf[23], wf[24], nullptr, nullptr, nullptr, nullptr, nullptr,
      nullptr, nullptr, nullptr, nullptr, nullptr, yff, nullptr, att, 0);

  ln2gap_kernel<<<4096, 256, 0, stream>>>(yff, wf[25], wf[26], outacc);
  fin_kernel<<<8, 256, 0, stream>>>(outacc, flag, d_out);
}

// Round 7
// 218.101 us; speedup vs baseline: 15.2629x; 1.3417x over previous
//
#include <hip/hip_runtime.h>
#include <hip/hip_bf16.h>
#include <math.h>

using bf16 = __hip_bfloat16;
typedef unsigned short u16;
typedef unsigned int u32;
typedef const float* __restrict__ cfp;

typedef __attribute__((ext_vector_type(8))) short short8v;
typedef __attribute__((ext_vector_type(4))) float f32x4;

static constexpr int kS = 1024, kE = 128, kH = 8, kDH = 16, kDFF = 512;
static constexpr float kEps = 1e-5f;

__device__ __forceinline__ float geluf(float x) { return 0.5f * x * (1.f + erff(x * 0.70710678118654752f)); }
__device__ __forceinline__ u16 f2b(float f) {
  u32 u = __float_as_uint(f);
  u32 r = (u + 0x7FFFu + ((u >> 16) & 1u)) >> 16;
  return (u16)r;
}

template<int N> __device__ __forceinline__ void wait_vmcnt() {
  asm volatile("s_waitcnt vmcnt(%0)" :: "n"(N) : "memory");
  __builtin_amdgcn_sched_barrier(0);
}

// ---------------- dtype detection (inputs bf16 vs f32) ----------------
__global__ void detect_kernel(const u16* __restrict__ xb, int n, int* __restrict__ flag) {
  int i = blockIdx.x * 256 + threadIdx.x;
  if (i >= n) return;
  int e = (xb[i] >> 7) & 0xFF;
  if (e >= 0xB5) *flag = 1;
}

struct CvtArgs { const void* p[27]; int cum[28]; };

__global__ void convert_kernel(CvtArgs a, const int* __restrict__ flag,
                               float* __restrict__ out, int total) {
  int idx = blockIdx.x * 256 + threadIdx.x;
  if (idx >= total) return;
  int id = 0;
  while (idx >= a.cum[id + 1]) ++id;
  int local = idx - a.cum[id];
  float v;
  if (*flag) v = ((const float*)a.p[id])[local];
  else       v = __bfloat162float(((const bf16*)a.p[id])[local]);
  out[idx] = v;
}

// ---------------- w2 f32 -> bf16, chunk-permuted for gload_lds swizzle ----------------
__global__ __launch_bounds__(256) void wcvt_kernel(cfp w2, u16* __restrict__ w2b) {
  int n = blockIdx.x;          // 0..127
  int ck = threadIdx.x;        // 16B chunk within row (0..255)
  const float* src = w2 + (size_t)n * 2048 + (size_t)ck * 8;
  float4 a = *(const float4*)src;
  float4 b = *(const float4*)(src + 4);
  short8v sv;
  sv[0] = (short)f2b(a.x); sv[1] = (short)f2b(a.y);
  sv[2] = (short)f2b(a.z); sv[3] = (short)f2b(a.w);
  sv[4] = (short)f2b(b.x); sv[5] = (short)f2b(b.y);
  sv[6] = (short)f2b(b.z); sv[7] = (short)f2b(b.w);
  int cd = (ck & ~7) | ((ck & 7) ^ (n & 7));
  *(short8v*)(w2b + (size_t)n * 2048 + cd * 8) = sv;
}

// ---------------- conv1+bn1+gelu -> Abuf bf16 [8192][2048], chunk-permuted ----------------
__global__ __launch_bounds__(256) void convstage_kernel(
    cfp x, cfp w1, cfp c1b, cfp g1, cfp b1, cfp m1, cfp v1,
    u16* __restrict__ Abuf, int grow0) {
  __shared__ float xs[8][4];
  int row = blockIdx.x;
  int grow = grow0 + row;
  int b = grow >> 10, s = grow & 1023;
  int tid = threadIdx.x;
  if (tid < 8) {
    int gs = s - 3 + tid;
    float4 xv = (gs >= 0 && gs < kS) ? ((const float4*)x)[b * kS + gs]
                                     : make_float4(0.f, 0.f, 0.f, 0.f);
    xs[tid][0] = xv.x; xs[tid][1] = xv.y; xs[tid][2] = xv.z; xs[tid][3] = xv.w;
  }
  __syncthreads();
  short8v outv;
#pragma unroll
  for (int cc = 0; cc < 2; ++cc) {
    int cx = tid * 2 + cc;
    float w[8];
#pragma unroll
    for (int t = 0; t < 8; ++t) w[t] = w1[cx * 8 + t];
    float sc = g1[cx] * __frsqrt_rn(v1[cx] + kEps);
    float ofs = b1[cx] - m1[cx] * sc;
    float cb = c1b[cx];
#pragma unroll
    for (int r = 0; r < 4; ++r) {
      float h = cb;
#pragma unroll
      for (int t = 0; t < 8; ++t) h += xs[t][r] * w[t];
      outv[cc * 4 + r] = (short)f2b(geluf(h * sc + ofs));
    }
  }
  int ck = (tid & ~7) | ((tid & 7) ^ (row & 7));
  *(short8v*)(Abuf + (size_t)row * 2048 + ck * 8) = outv;
}

// ---------------- rel-bias MFMA fragment table ----------------
__global__ __launch_bounds__(64) void rbtab_kernel(cfp relb, u16* __restrict__ T) {
  int t = blockIdx.x, h = blockIdx.y;
  int l = threadIdx.x;
  int lr = l & 15, lg = l >> 4;
  short8v v;
#pragma unroll
  for (int e = 0; e < 8; ++e) {
    int idx = 16 * t + 31 + lr - 8 * lg - e;
    v[e] = (short)f2b(relb[idx * 8 + h]);
  }
  *(short8v*)(T + ((size_t)(h * 126 + t) * 64 + l) * 8) = v;
}

// =====================================================================
// Pipelined conv GEMM: C[16384,128] = Abuf[.,2048] x w2b[128,2048]^T
// BM=32, BN=128, BK=64; 4 waves, wave-tile 16x64; 3-deep gload_lds pipeline.
// Abuf/w2b are chunk-permuted so linear LDS writes give the XOR-swizzle.
// =====================================================================
__global__ __launch_bounds__(256, 2) void convgemm_kernel(
    const u16* __restrict__ Abuf, const u16* __restrict__ w2b,
    cfp c2b, cfp g2, cfp b2, cfp m2, cfp v2,
    float* __restrict__ xsrc, u16* __restrict__ xpeb, int mbase) {
  __shared__ short8v lds[3840];        // 3 x (256 A-chunks + 1024 B-chunks)
  const int tid = threadIdx.x;
  const int mtile = blockIdx.x;
  const int wid = tid >> 6, lane = tid & 63;
  const int lrow = lane & 15, lk = lane >> 4;
  const int m0w = (wid & 1) * 16, n0w = (wid >> 1) * 64;

  // preload epilogue constants so no VMEM op lands inside the vmcnt-counted loop
  float scn[4], cc[4], dv[4];
#pragma unroll
  for (int ni = 0; ni < 4; ++ni) {
    int n = n0w + ni * 16 + lrow;
    scn[ni] = g2[n] * __frsqrt_rn(v2[n] + kEps);
    cc[ni] = (c2b[n] - m2[n]) * scn[ni] + b2[n];
    dv[ni] = __expf((float)(n >> 1) * (-0.14391156824963732f)) * 0.125f;
  }

  f32x4 acc[4];
#pragma unroll
  for (int ni = 0; ni < 4; ++ni) acc[ni] = (f32x4){0.f, 0.f, 0.f, 0.f};

  const int q = wid * 64 + lane;
  const u16* aG = Abuf + (size_t)(mtile * 32 + (q >> 3)) * 2048 + (q & 7) * 8;

  auto stage = [&](int t) {
    int buf = t % 3;
    short8v* A = lds + buf * 1280;
    __builtin_amdgcn_global_load_lds(
        (const __attribute__((address_space(1))) void*)(aG + t * 64),
        (__attribute__((address_space(3))) void*)(A + wid * 64), 16, 0, 0);
#pragma unroll
    for (int r = 0; r < 4; ++r) {
      int qq = r * 256 + q;
      const u16* g = w2b + (size_t)(qq >> 3) * 2048 + t * 64 + (qq & 7) * 8;
      __builtin_amdgcn_global_load_lds(
          (const __attribute__((address_space(1))) void*)g,
          (__attribute__((address_space(3))) void*)(A + 256 + r * 256 + wid * 64), 16, 0, 0);
    }
  };

  auto compute = [&](int t) {
    int buf = t % 3;
    const short8v* A = lds + buf * 1280;
    const short8v* B = A + 256;
#pragma unroll
    for (int ks = 0; ks < 2; ++ks) {
      int ar = m0w + lrow;
      u32 ao = ((u32)(ar * 128 + ks * 64 + lk * 16)) ^ ((u32)((ar & 7) << 4));
      short8v af = A[ao >> 4];
#pragma unroll
      for (int ni = 0; ni < 4; ++ni) {
        int br = n0w + ni * 16 + lrow;
        u32 bo = ((u32)(br * 128 + ks * 64 + lk * 16)) ^ ((u32)((br & 7) << 4));
        short8v bf = B[bo >> 4];
        acc[ni] = __builtin_amdgcn_mfma_f32_16x16x32_bf16(af, bf, acc[ni], 0, 0, 0);
      }
    }
  };

  stage(0); stage(1); stage(2);
  for (int t = 0; t < 30; ++t) {
    wait_vmcnt<10>();
    __builtin_amdgcn_s_barrier();
    __builtin_amdgcn_sched_barrier(0);
    compute(t);
    asm volatile("" ::: "memory");
    __builtin_amdgcn_s_barrier();
    __builtin_amdgcn_sched_barrier(0);
    if (t <= 28) stage(t + 3);
  }
  wait_vmcnt<5>();
  __builtin_amdgcn_s_barrier();
  __builtin_amdgcn_sched_barrier(0);
  compute(30);
  asm volatile("" ::: "memory");
  __builtin_amdgcn_s_barrier();
  __builtin_amdgcn_sched_barrier(0);
  wait_vmcnt<0>();
  __builtin_amdgcn_s_barrier();
  __builtin_amdgcn_sched_barrier(0);
  compute(31);

  // epilogue: +c2b, bn2, gelu -> xsrc f32 ; +PE -> xpeb bf16
#pragma unroll
  for (int ni = 0; ni < 4; ++ni) {
    int n = n0w + ni * 16 + lrow;
#pragma unroll
    for (int r = 0; r < 4; ++r) {
      int grow = mbase + mtile * 32 + m0w + lk * 4 + r;
      float gv = geluf(acc[ni][r] * scn[ni] + cc[ni]);
      xsrc[(size_t)grow * kE + n] = gv;
      int s = grow & 1023;
      float ang = (float)s * dv[ni];
      float pe = (n & 1) ? __cosf(ang) : __sinf(ang);
      xpeb[(size_t)grow * kE + n] = f2b(gv + pe);
    }
  }
}

// =====================================================================
// bf16 MFMA GEMM (QKV / FF1 / FF2 — unchanged, proven)
// =====================================================================
template<int ASRC, int MODE, int KTOT, int BM>
__global__ __launch_bounds__(256, 4) void gemm_kernel(
    const void* __restrict__ Ap, cfp Wf,
    cfp p0, cfp p1, cfp p2, cfp p3, cfp p4, cfp p5,
    cfp p6, cfp p7, cfp p8, cfp p9, cfp p10,
    void* __restrict__ Out, void* __restrict__ Out2, cfp res, int mbase) {
  constexpr int MI = BM / 32;
  __shared__ short8v Ab[BM * 8];
  __shared__ short8v Bb[512];

  int tid = threadIdx.x;
  int mtile = blockIdx.x, ntile = blockIdx.y;

  cfp Wsel = Wf;
  if (MODE == 1) Wsel = (blockIdx.z == 0) ? Wf : ((blockIdx.z == 1) ? p1 : p2);

  int wid = tid >> 6, lane = tid & 63;
  int m0w = (wid >> 1) * (BM / 2), n0w = (wid & 1) * 32;
  int lrow = lane & 15, lk = lane >> 4;

  f32x4 acc[MI][2];
#pragma unroll
  for (int mi = 0; mi < MI; ++mi)
#pragma unroll
    for (int ni = 0; ni < 2; ++ni) acc[mi][ni] = (f32x4){0.f, 0.f, 0.f, 0.f};

  for (int k0 = 0; k0 < KTOT; k0 += 64) {
    __syncthreads();
#pragma unroll
    for (int c = 0; c < BM / 32; ++c) {
      int chunk = tid + 256 * c;
      int row = chunk >> 3, kc = chunk & 7;
      int arow = mtile * BM + row;
      u32 off = ((u32)(row * 128 + kc * 16)) ^ ((u32)((row & 7) << 4));
      const u16* As = (const u16*)Ap + (size_t)arow * KTOT + k0 + kc * 8;
      Ab[off >> 4] = *(const short8v*)As;
    }
#pragma unroll
    for (int c = 0; c < 2; ++c) {
      int chunk = tid + 256 * c;
      int row = chunk >> 3, kc = chunk & 7;
      const float* Wp = Wsel + (size_t)(ntile * 64 + row) * KTOT + k0 + kc * 8;
      float4 xa = *(const float4*)Wp;
      float4 xb = *(const float4*)(Wp + 4);
      short8v sv;
      sv[0] = (short)f2b(xa.x); sv[1] = (short)f2b(xa.y);
      sv[2] = (short)f2b(xa.z); sv[3] = (short)f2b(xa.w);
      sv[4] = (short)f2b(xb.x); sv[5] = (short)f2b(xb.y);
      sv[6] = (short)f2b(xb.z); sv[7] = (short)f2b(xb.w);
      u32 off = ((u32)(row * 128 + kc * 16)) ^ ((u32)((row & 7) << 4));
      Bb[off >> 4] = sv;
    }
    __syncthreads();
#pragma unroll
    for (int ks = 0; ks < 2; ++ks) {
      short8v af[MI], bfr[2];
#pragma unroll
      for (int mi = 0; mi < MI; ++mi) {
        int row = m0w + mi * 16 + lrow;
        u32 off = ((u32)(row * 128 + ks * 64 + lk * 16)) ^ ((u32)((row & 7) << 4));
        af[mi] = Ab[off >> 4];
      }
#pragma unroll
      for (int ni = 0; ni < 2; ++ni) {
        int row = n0w + ni * 16 + lrow;
        u32 off = ((u32)(row * 128 + ks * 64 + lk * 16)) ^ ((u32)((row & 7) << 4));
        bfr[ni] = Bb[off >> 4];
      }
#pragma unroll
      for (int mi = 0; mi < MI; ++mi)
#pragma unroll
        for (int ni = 0; ni < 2; ++ni)
          acc[mi][ni] = __builtin_amdgcn_mfma_f32_16x16x32_bf16(af[mi], bfr[ni], acc[mi][ni], 0, 0, 0);
    }
  }

#pragma unroll
  for (int ni = 0; ni < 2; ++ni) {
    int n = ntile * 64 + n0w + ni * 16 + lrow;
    float c0 = 0.f;
    if (MODE == 2 || MODE == 3) c0 = p0[n];
#pragma unroll
    for (int mi = 0; mi < MI; ++mi) {
#pragma unroll
      for (int r = 0; r < 4; ++r) {
        int grow = mbase + mtile * BM + m0w + mi * 16 + lk * 4 + r;
        float val = acc[mi][ni][r];
        if (MODE == 1) {
          int s = grow & 1023, b_ = grow >> 10;
          u16* ob = (u16*)Out + (size_t)blockIdx.z * 2097152;
          ob[(((size_t)(b_ * kH + (n >> 4))) * kS + s) * kDH + (n & 15)] = f2b(val);
        } else if (MODE == 2) {
          ((u16*)Out)[(size_t)grow * kDFF + n] = f2b(fmaxf(val + c0, 0.f));
        } else {
          ((float*)Out)[(size_t)grow * kE + n] = val + c0 + res[(size_t)grow * kE + n];
        }
      }
    }
  }
}

// =====================================================================
// MFMA attention (unchanged — proven)
// =====================================================================
__global__ __launch_bounds__(512, 4) void attn_kernel(
    const u16* __restrict__ qb, const u16* __restrict__ kb,
    const u16* __restrict__ vb, const u16* __restrict__ rbT,
    float* __restrict__ o) {
  __shared__ u16 Vsh[16 * 1032];
  __shared__ u16 Pt[8][1280];

  int tid = threadIdx.x;
  int quarter = blockIdx.x & 3;
  int h = (blockIdx.x >> 2) & 7;
  int bb = blockIdx.x >> 5;
  size_t base = (size_t)(bb * kH + h) * (kS * kDH);

  for (int j = tid; j < 1024; j += 512) {
    const uint4* src = (const uint4*)(vb + base + j * 16);
    uint4 a = src[0], b = src[1];
    u32 wv[8] = {a.x, a.y, a.z, a.w, b.x, b.y, b.z, b.w};
#pragma unroll
    for (int p = 0; p < 8; ++p) {
      Vsh[(2 * p) * 1032 + j]     = (u16)(wv[p] & 0xFFFFu);
      Vsh[(2 * p + 1) * 1032 + j] = (u16)(wv[p] >> 16);
    }
  }
  __syncthreads();

  int w = tid >> 6, l = tid & 63;
  int lr = l & 15, lg = l >> 4;
  u16* P = Pt[w];
  int q0w = quarter * 256 + w * 32;
  int tbase = (q0w + 992) >> 4;
  const float cs = 0.088388347648318447f;
  const u16* rbh = rbT + (size_t)h * 126 * 512;

  short8v qf[2];
#pragma unroll
  for (int qt = 0; qt < 2; ++qt) {
    qf[qt] = (short8v){0, 0, 0, 0, 0, 0, 0, 0};
    if (lg < 2)
      qf[qt] = *(const short8v*)(qb + base + (size_t)(q0w + qt * 16 + lr) * 16 + lg * 8);
  }
  f32x4 acc_e[2], acc_rb[2];
  float lac[2] = {0.f, 0.f};
#pragma unroll
  for (int qt = 0; qt < 2; ++qt) {
    acc_e[qt] = (f32x4){0.f, 0.f, 0.f, 0.f};
    acc_rb[qt] = (f32x4){0.f, 0.f, 0.f, 0.f};
  }

  for (int jb = 0; jb < 32; ++jb) {
    short8v kf0 = (short8v){0, 0, 0, 0, 0, 0, 0, 0};
    short8v kf1 = (short8v){0, 0, 0, 0, 0, 0, 0, 0};
    if (lg < 2) {
      kf0 = *(const short8v*)(kb + base + (size_t)(jb * 32 + lr) * 16 + lg * 8);
      kf1 = *(const short8v*)(kb + base + (size_t)(jb * 32 + 16 + lr) * 16 + lg * 8);
    }
    short8v vf = *(const short8v*)(Vsh + lr * 1032 + jb * 32 + lg * 8);
#pragma unroll
    for (int qt = 0; qt < 2; ++qt) {
      f32x4 s0 = __builtin_amdgcn_mfma_f32_16x16x32_bf16(kf0, qf[qt], (f32x4){0.f, 0.f, 0.f, 0.f}, 0, 0, 0);
      f32x4 s1 = __builtin_amdgcn_mfma_f32_16x16x32_bf16(kf1, qf[qt], (f32x4){0.f, 0.f, 0.f, 0.f}, 0, 0, 0);
      float e0 = __expf(s0[0] * cs), e1 = __expf(s0[1] * cs);
      float e2 = __expf(s0[2] * cs), e3 = __expf(s0[3] * cs);
      float f0 = __expf(s1[0] * cs), f1 = __expf(s1[1] * cs);
      float f2 = __expf(s1[2] * cs), f3 = __expf(s1[3] * cs);
      lac[qt] += (e0 + e1) + (e2 + e3) + (f0 + f1) + (f2 + f3);
      uint2 w0, w1;
      w0.x = (u32)f2b(e0) | ((u32)f2b(e1) << 16);
      w0.y = (u32)f2b(e2) | ((u32)f2b(e3) << 16);
      w1.x = (u32)f2b(f0) | ((u32)f2b(f1) << 16);
      w1.y = (u32)f2b(f2) | ((u32)f2b(f3) << 16);
      int prow = (qt * 16 + lr) * 40;
      *(uint2*)(P + prow + 4 * lg)      = w0;
      *(uint2*)(P + prow + 16 + 4 * lg) = w1;
      short8v pf = *(const short8v*)(P + (qt * 16 + lr) * 40 + lg * 8);
      int t = tbase + qt - 2 * jb;
      short8v rf = *(const short8v*)(rbh + ((size_t)t * 64 + l) * 8);
      acc_e[qt]  = __builtin_amdgcn_mfma_f32_16x16x32_bf16(pf, vf, acc_e[qt], 0, 0, 0);
      acc_rb[qt] = __builtin_amdgcn_mfma_f32_16x16x32_bf16(rf, vf, acc_rb[qt], 0, 0, 0);
    }
  }

#pragma unroll
  for (int qt = 0; qt < 2; ++qt) {
    float ls = lac[qt];
    ls += __shfl_xor(ls, 16);
    ls += __shfl_xor(ls, 32);
#pragma unroll
    for (int r = 0; r < 4; ++r) {
      float lsq = __shfl(ls, lg * 4 + r);
      int row = q0w + qt * 16 + lg * 4 + r;
      o[(size_t)(bb * kS + row) * kE + h * kDH + lr] = acc_e[qt][r] / lsq + acc_rb[qt][r];
    }
  }
}

// ---------------- LN(attn out) + residual + LN1 -> att (f32 + bf16) ----------------
__global__ __launch_bounds__(256) void ln_kernel(
    cfp o, cfp xsrc, cfp lag, cfp lab, cfp l1g, cfp l1b,
    float* __restrict__ att, u16* __restrict__ attb) {
  int row = blockIdx.x * 4 + (threadIdx.x >> 6);
  int lane = threadIdx.x & 63;
  float2 a = ((const float2*)(o + (size_t)row * kE))[lane];
  float sum = a.x + a.y;
  for (int off = 1; off < 64; off <<= 1) sum += __shfl_xor(sum, off);
  float mean = sum * (1.f / 128.f);
  float d0 = a.x - mean, d1 = a.y - mean;
  float ss = d0 * d0 + d1 * d1;
  for (int off = 1; off < 64; off <<= 1) ss += __shfl_xor(ss, off);
  float inv = 1.f / sqrtf(ss * (1.f / 128.f) + kEps);
  float t0 = d0 * inv * lag[2 * lane] + lab[2 * lane];
  float t1 = d1 * inv * lag[2 * lane + 1] + lab[2 * lane + 1];
  float2 xv = ((const float2*)(xsrc + (size_t)row * kE))[lane];
  t0 += xv.x; t1 += xv.y;
  float sum2 = t0 + t1;
  for (int off = 1; off < 64; off <<= 1) sum2 += __shfl_xor(sum2, off);
  float mean2 = sum2 * (1.f / 128.f);
  float e0 = t0 - mean2, e1 = t1 - mean2;
  float ss2 = e0 * e0 + e1 * e1;
  for (int off = 1; off < 64; off <<= 1) ss2 += __shfl_xor(ss2, off);
  float inv2 = 1.f / sqrtf(ss2 * (1.f / 128.f) + kEps);
  float r0 = e0 * inv2 * l1g[2 * lane] + l1b[2 * lane];
  float r1 = e1 * inv2 * l1g[2 * lane + 1] + l1b[2 * lane + 1];
  ((float2*)(att + (size_t)row * kE))[lane] = make_float2(r0, r1);
  ((u32*)attb)[(size_t)row * 64 + lane] = (u32)f2b(r0) | ((u32)f2b(r1) << 16);
}

// ---------------- LN2 + GAP ----------------
__global__ __launch_bounds__(256) void ln2gap_kernel(
    cfp yff, cfp l2g, cfp l2b, float* __restrict__ outacc) {
  __shared__ float red[128];
  int tid = threadIdx.x;
  if (tid < 128) red[tid] = 0.f;
  __syncthreads();
  int row = blockIdx.x * 4 + (tid >> 6);
  int lane = tid & 63;
  float2 a = ((const float2*)(yff + (size_t)row * kE))[lane];
  float sum = a.x + a.y;
  for (int off = 1; off < 64; off <<= 1) sum += __shfl_xor(sum, off);
  float mean = sum * (1.f / 128.f);
  float d0 = a.x - mean, d1 = a.y - mean;
  float ss = d0 * d0 + d1 * d1;
  for (int off = 1; off < 64; off <<= 1) ss += __shfl_xor(ss, off);
  float inv = 1.f / sqrtf(ss * (1.f / 128.f) + kEps);
  float r0 = d0 * inv * l2g[2 * lane] + l2b[2 * lane];
  float r1 = d1 * inv * l2g[2 * lane + 1] + l2b[2 * lane + 1];
  atomicAdd(&red[2 * lane], r0);
  atomicAdd(&red[2 * lane + 1], r1);
  __syncthreads();
  int bb = (blockIdx.x * 4) >> 10;
  if (tid < 128) atomicAdd(&outacc[bb * kE + tid], red[tid]);
}

// ---------------- finalize ----------------
__global__ void fin_kernel(cfp outacc, const int* __restrict__ flag, void* __restrict__ out) {
  int i = blockIdx.x * 256 + threadIdx.x;
  float v = outacc[i] * (1.f / 1024.f);
  if (*flag) ((float*)out)[i] = v;
  else       ((bf16*)out)[i] = __float2bfloat16(v);
}

extern "C" void kernel_launch(void* const* d_in, const int* in_sizes, int n_in,
                              void* d_out, int out_size, void* d_ws, size_t ws_size,
                              hipStream_t stream) {
  CvtArgs args;
  int cum = 0;
  for (int i = 0; i < n_in && i < 27; ++i) {
    args.p[i] = d_in[i];
    args.cum[i] = cum;
    cum += in_sizes[i];
  }
  args.cum[n_in] = cum;
  int total = cum;
  int totalPad = (total + 15) & ~15;

  float* ws = (float*)d_ws;
  int* flag    = (int*)ws;
  float* wsinf = ws + 16;
  float* xsrc  = wsinf + totalPad;               // 2,097,152 f32
  float* att   = xsrc + 2097152;                 // 2,097,152 f32
  float* qkv0  = att + 2097152;                  // 3,145,728 (q,k,v bf16)
  float* ext   = qkv0 + 3145728;                 // 1,048,576 (rbT; ff1b tail)
  float* o     = ext + 1048576;                  // 2,097,152 (later yff)
  float* outacc = o + 2097152;                   // 2,048
  u16* xpeb    = (u16*)(outacc + 2048);          // 2,097,152 u16
  u16* w2b     = xpeb + 2097152;                 // 262,144 u16 (0.5 MB)

  u16* Abuf = (u16*)att;                         // overlays att..o exactly (8,388,608 f32)
  u16* qb = (u16*)qkv0;
  u16* kb = qb + 2097152;
  u16* vb = kb + 2097152;
  u16* rbT = (u16*)ext;
  u16* ff1b = (u16*)qkv0;
  u16* attb = xpeb;
  float* yff = o;

  const float* wf[27];
  for (int i = 0; i < n_in && i < 27; ++i) wf[i] = wsinf + args.cum[i];

  hipMemsetAsync(flag, 0, sizeof(int), stream);
  hipMemsetAsync(outacc, 0, 2048 * sizeof(float), stream);
  detect_kernel<<<(in_sizes[0] + 255) / 256, 256, 0, stream>>>(
      (const u16*)d_in[0], in_sizes[0], flag);
  convert_kernel<<<(total + 255) / 256, 256, 0, stream>>>(args, flag, wsinf, total);
  wcvt_kernel<<<128, 256, 0, stream>>>(wf[7], w2b);

  // conv1+bn1+gelu staged to bf16 (chunk-permuted), then pipelined MFMA GEMM
  for (int hm = 0; hm < 2; ++hm) {
    convstage_kernel<<<8192, 256, 0, stream>>>(
        wf[0], wf[1], wf[2], wf[3], wf[4], wf[5], wf[6], Abuf, hm * 8192);
    convgemm_kernel<<<256, 256, 0, stream>>>(
        Abuf, w2b, wf[8], wf[9], wf[10], wf[11], wf[12], xsrc, xpeb, hm * 8192);
  }

  rbtab_kernel<<<dim3(126, 8), 64, 0, stream>>>(wf[16], rbT);

  gemm_kernel<3, 1, 128, 128><<<dim3(128, 2, 3), 256, 0, stream>>>(
      xpeb, wf[13], nullptr, wf[14], wf[15], nullptr, nullptr, nullptr,
      nullptr, nullptr, nullptr, nullptr, nullptr, qb, nullptr, nullptr, 0);

  attn_kernel<<<512, 512, 0, stream>>>(qb, kb, vb, rbT, o);
  ln_kernel<<<4096, 256, 0, stream>>>(o, xsrc, wf[17], wf[18], wf[19], wf[20], att, attb);

  gemm_kernel<3, 2, 128, 128><<<dim3(128, 8), 256, 0, stream>>>(
      attb, wf[21], wf[22], nullptr, nullptr, nullptr, nullptr, nullptr,
      nullptr, nullptr, nullptr, nullptr, nullptr, ff1b, nullptr, nullptr, 0);
  gemm_kernel<3, 3, 512, 128><<<dim3(128, 2), 256, 0, stream>>>(
      ff1b, wf[23], wf[24], nullptr, nullptr, nullptr, nullptr, nullptr,
      nullptr, nullptr, nullptr, nullptr, nullptr, yff, nullptr, att, 0);

  ln2gap_kernel<<<4096, 256, 0, stream>>>(yff, wf[25], wf[26], outacc);
  fin_kernel<<<8, 256, 0, stream>>>(outacc, flag, d_out);
}

// Round 8
// 214.310 us; speedup vs baseline: 15.5328x; 1.0177x over previous
//
#include <hip/hip_runtime.h>
#include <hip/hip_bf16.h>
#include <math.h>

using bf16 = __hip_bfloat16;
typedef unsigned short u16;
typedef unsigned int u32;
typedef const float* __restrict__ cfp;

typedef __attribute__((ext_vector_type(8))) short short8v;
typedef __attribute__((ext_vector_type(4))) float f32x4;
typedef __attribute__((ext_vector_type(16))) float f32x16;

static constexpr int kS = 1024, kE = 128, kH = 8, kDH = 16, kDFF = 512;
static constexpr float kEps = 1e-5f;

__device__ __forceinline__ float geluf(float x) { return 0.5f * x * (1.f + erff(x * 0.70710678118654752f)); }
__device__ __forceinline__ u16 f2b(float f) {
  u32 u = __float_as_uint(f);
  u32 r = (u + 0x7FFFu + ((u >> 16) & 1u)) >> 16;
  return (u16)r;
}

template<int N> __device__ __forceinline__ void wait_vmcnt() {
  asm volatile("s_waitcnt vmcnt(%0)" :: "n"(N) : "memory");
  __builtin_amdgcn_sched_barrier(0);
}

// ---------------- dtype detection (inputs bf16 vs f32) ----------------
__global__ void detect_kernel(const u16* __restrict__ xb, int n, int* __restrict__ flag) {
  int i = blockIdx.x * 256 + threadIdx.x;
  if (i >= n) return;
  int e = (xb[i] >> 7) & 0xFF;
  if (e >= 0xB5) *flag = 1;
}

struct CvtArgs { const void* p[27]; int cum[28]; };

__global__ void convert_kernel(CvtArgs a, const int* __restrict__ flag,
                               float* __restrict__ out, int total) {
  int idx = blockIdx.x * 256 + threadIdx.x;
  if (idx >= total) return;
  int id = 0;
  while (idx >= a.cum[id + 1]) ++id;
  int local = idx - a.cum[id];
  float v;
  if (*flag) v = ((const float*)a.p[id])[local];
  else       v = __bfloat162float(((const bf16*)a.p[id])[local]);
  out[idx] = v;
}

// ---------------- w2 f32 -> bf16, chunk-permuted for gload_lds swizzle ----------------
__global__ __launch_bounds__(256) void wcvt_kernel(cfp w2, u16* __restrict__ w2b) {
  int n = blockIdx.x;
  int ck = threadIdx.x;
  const float* src = w2 + (size_t)n * 2048 + (size_t)ck * 8;
  float4 a = *(const float4*)src;
  float4 b = *(const float4*)(src + 4);
  short8v sv;
  sv[0] = (short)f2b(a.x); sv[1] = (short)f2b(a.y);
  sv[2] = (short)f2b(a.z); sv[3] = (short)f2b(a.w);
  sv[4] = (short)f2b(b.x); sv[5] = (short)f2b(b.y);
  sv[6] = (short)f2b(b.z); sv[7] = (short)f2b(b.w);
  int cd = (ck & ~7) | ((ck & 7) ^ (n & 7));
  *(short8v*)(w2b + (size_t)n * 2048 + cd * 8) = sv;
}

// ---------------- conv1+bn1+gelu -> Abuf bf16 [8192][2048], chunk-permuted ----------------
__global__ __launch_bounds__(256) void convstage_kernel(
    cfp x, cfp w1, cfp c1b, cfp g1, cfp b1, cfp m1, cfp v1,
    u16* __restrict__ Abuf, int grow0) {
  __shared__ float xs[8][4];
  int row = blockIdx.x;
  int grow = grow0 + row;
  int b = grow >> 10, s = grow & 1023;
  int tid = threadIdx.x;
  if (tid < 8) {
    int gs = s - 3 + tid;
    float4 xv = (gs >= 0 && gs < kS) ? ((const float4*)x)[b * kS + gs]
                                     : make_float4(0.f, 0.f, 0.f, 0.f);
    xs[tid][0] = xv.x; xs[tid][1] = xv.y; xs[tid][2] = xv.z; xs[tid][3] = xv.w;
  }
  __syncthreads();
  short8v outv;
#pragma unroll
  for (int cc = 0; cc < 2; ++cc) {
    int cx = tid * 2 + cc;
    float w[8];
#pragma unroll
    for (int t = 0; t < 8; ++t) w[t] = w1[cx * 8 + t];
    float sc = g1[cx] * __frsqrt_rn(v1[cx] + kEps);
    float ofs = b1[cx] - m1[cx] * sc;
    float cb = c1b[cx];
#pragma unroll
    for (int r = 0; r < 4; ++r) {
      float h = cb;
#pragma unroll
      for (int t = 0; t < 8; ++t) h += xs[t][r] * w[t];
      outv[cc * 4 + r] = (short)f2b(geluf(h * sc + ofs));
    }
  }
  int ck = (tid & ~7) | ((tid & 7) ^ (row & 7));
  *(short8v*)(Abuf + (size_t)row * 2048 + ck * 8) = outv;
}

// ---------------- rel-bias MFMA fragment table ----------------
__global__ __launch_bounds__(64) void rbtab_kernel(cfp relb, u16* __restrict__ T) {
  int t = blockIdx.x, h = blockIdx.y;
  int l = threadIdx.x;
  int lr = l & 15, lg = l >> 4;
  short8v v;
#pragma unroll
  for (int e = 0; e < 8; ++e) {
    int idx = 16 * t + 31 + lr - 8 * lg - e;
    v[e] = (short)f2b(relb[idx * 8 + h]);
  }
  *(short8v*)(T + ((size_t)(h * 126 + t) * 64 + l) * 8) = v;
}

// =====================================================================
// Pipelined conv GEMM (unchanged — proven)
// =====================================================================
__global__ __launch_bounds__(256, 2) void convgemm_kernel(
    const u16* __restrict__ Abuf, const u16* __restrict__ w2b,
    cfp c2b, cfp g2, cfp b2, cfp m2, cfp v2,
    float* __restrict__ xsrc, u16* __restrict__ xpeb, int mbase) {
  __shared__ short8v lds[3840];
  const int tid = threadIdx.x;
  const int mtile = blockIdx.x;
  const int wid = tid >> 6, lane = tid & 63;
  const int lrow = lane & 15, lk = lane >> 4;
  const int m0w = (wid & 1) * 16, n0w = (wid >> 1) * 64;

  float scn[4], cc[4], dv[4];
#pragma unroll
  for (int ni = 0; ni < 4; ++ni) {
    int n = n0w + ni * 16 + lrow;
    scn[ni] = g2[n] * __frsqrt_rn(v2[n] + kEps);
    cc[ni] = (c2b[n] - m2[n]) * scn[ni] + b2[n];
    dv[ni] = __expf((float)(n >> 1) * (-0.14391156824963732f)) * 0.125f;
  }

  f32x4 acc[4];
#pragma unroll
  for (int ni = 0; ni < 4; ++ni) acc[ni] = (f32x4){0.f, 0.f, 0.f, 0.f};

  const int q = wid * 64 + lane;
  const u16* aG = Abuf + (size_t)(mtile * 32 + (q >> 3)) * 2048 + (q & 7) * 8;

  auto stage = [&](int t) {
    int buf = t % 3;
    short8v* A = lds + buf * 1280;
    __builtin_amdgcn_global_load_lds(
        (const __attribute__((address_space(1))) void*)(aG + t * 64),
        (__attribute__((address_space(3))) void*)(A + wid * 64), 16, 0, 0);
#pragma unroll
    for (int r = 0; r < 4; ++r) {
      int qq = r * 256 + q;
      const u16* g = w2b + (size_t)(qq >> 3) * 2048 + t * 64 + (qq & 7) * 8;
      __builtin_amdgcn_global_load_lds(
          (const __attribute__((address_space(1))) void*)g,
          (__attribute__((address_space(3))) void*)(A + 256 + r * 256 + wid * 64), 16, 0, 0);
    }
  };

  auto compute = [&](int t) {
    int buf = t % 3;
    const short8v* A = lds + buf * 1280;
    const short8v* B = A + 256;
#pragma unroll
    for (int ks = 0; ks < 2; ++ks) {
      int ar = m0w + lrow;
      u32 ao = ((u32)(ar * 128 + ks * 64 + lk * 16)) ^ ((u32)((ar & 7) << 4));
      short8v af = A[ao >> 4];
#pragma unroll
      for (int ni = 0; ni < 4; ++ni) {
        int br = n0w + ni * 16 + lrow;
        u32 bo = ((u32)(br * 128 + ks * 64 + lk * 16)) ^ ((u32)((br & 7) << 4));
        short8v bf = B[bo >> 4];
        acc[ni] = __builtin_amdgcn_mfma_f32_16x16x32_bf16(af, bf, acc[ni], 0, 0, 0);
      }
    }
  };

  stage(0); stage(1); stage(2);
  for (int t = 0; t < 30; ++t) {
    wait_vmcnt<10>();
    __builtin_amdgcn_s_barrier();
    __builtin_amdgcn_sched_barrier(0);
    compute(t);
    asm volatile("" ::: "memory");
    __builtin_amdgcn_s_barrier();
    __builtin_amdgcn_sched_barrier(0);
    if (t <= 28) stage(t + 3);
  }
  wait_vmcnt<5>();
  __builtin_amdgcn_s_barrier();
  __builtin_amdgcn_sched_barrier(0);
  compute(30);
  asm volatile("" ::: "memory");
  __builtin_amdgcn_s_barrier();
  __builtin_amdgcn_sched_barrier(0);
  wait_vmcnt<0>();
  __builtin_amdgcn_s_barrier();
  __builtin_amdgcn_sched_barrier(0);
  compute(31);

#pragma unroll
  for (int ni = 0; ni < 4; ++ni) {
    int n = n0w + ni * 16 + lrow;
#pragma unroll
    for (int r = 0; r < 4; ++r) {
      int grow = mbase + mtile * 32 + m0w + lk * 4 + r;
      float gv = geluf(acc[ni][r] * scn[ni] + cc[ni]);
      xsrc[(size_t)grow * kE + n] = gv;
      int s = grow & 1023;
      float ang = (float)s * dv[ni];
      float pe = (n & 1) ? __cosf(ang) : __sinf(ang);
      xpeb[(size_t)grow * kE + n] = f2b(gv + pe);
    }
  }
}

// =====================================================================
// bf16 MFMA GEMM (QKV / FF1 / FF2). MODE==1 z==0 (Q) pre-scaled by
// 128^-0.5 * log2(e) so attention can use exp2 directly.
// =====================================================================
template<int ASRC, int MODE, int KTOT, int BM>
__global__ __launch_bounds__(256, 4) void gemm_kernel(
    const void* __restrict__ Ap, cfp Wf,
    cfp p0, cfp p1, cfp p2, cfp p3, cfp p4, cfp p5,
    cfp p6, cfp p7, cfp p8, cfp p9, cfp p10,
    void* __restrict__ Out, void* __restrict__ Out2, cfp res, int mbase) {
  constexpr int MI = BM / 32;
  __shared__ short8v Ab[BM * 8];
  __shared__ short8v Bb[512];

  int tid = threadIdx.x;
  int mtile = blockIdx.x, ntile = blockIdx.y;

  cfp Wsel = Wf;
  if (MODE == 1) Wsel = (blockIdx.z == 0) ? Wf : ((blockIdx.z == 1) ? p1 : p2);

  int wid = tid >> 6, lane = tid & 63;
  int m0w = (wid >> 1) * (BM / 2), n0w = (wid & 1) * 32;
  int lrow = lane & 15, lk = lane >> 4;

  f32x4 acc[MI][2];
#pragma unroll
  for (int mi = 0; mi < MI; ++mi)
#pragma unroll
    for (int ni = 0; ni < 2; ++ni) acc[mi][ni] = (f32x4){0.f, 0.f, 0.f, 0.f};

  for (int k0 = 0; k0 < KTOT; k0 += 64) {
    __syncthreads();
#pragma unroll
    for (int c = 0; c < BM / 32; ++c) {
      int chunk = tid + 256 * c;
      int row = chunk >> 3, kc = chunk & 7;
      int arow = mtile * BM + row;
      u32 off = ((u32)(row * 128 + kc * 16)) ^ ((u32)((row & 7) << 4));
      const u16* As = (const u16*)Ap + (size_t)arow * KTOT + k0 + kc * 8;
      Ab[off >> 4] = *(const short8v*)As;
    }
#pragma unroll
    for (int c = 0; c < 2; ++c) {
      int chunk = tid + 256 * c;
      int row = chunk >> 3, kc = chunk & 7;
      const float* Wp = Wsel + (size_t)(ntile * 64 + row) * KTOT + k0 + kc * 8;
      float4 xa = *(const float4*)Wp;
      float4 xb = *(const float4*)(Wp + 4);
      short8v sv;
      sv[0] = (short)f2b(xa.x); sv[1] = (short)f2b(xa.y);
      sv[2] = (short)f2b(xa.z); sv[3] = (short)f2b(xa.w);
      sv[4] = (short)f2b(xb.x); sv[5] = (short)f2b(xb.y);
      sv[6] = (short)f2b(xb.z); sv[7] = (short)f2b(xb.w);
      u32 off = ((u32)(row * 128 + kc * 16)) ^ ((u32)((row & 7) << 4));
      Bb[off >> 4] = sv;
    }
    __syncthreads();
#pragma unroll
    for (int ks = 0; ks < 2; ++ks) {
      short8v af[MI], bfr[2];
#pragma unroll
      for (int mi = 0; mi < MI; ++mi) {
        int row = m0w + mi * 16 + lrow;
        u32 off = ((u32)(row * 128 + ks * 64 + lk * 16)) ^ ((u32)((row & 7) << 4));
        af[mi] = Ab[off >> 4];
      }
#pragma unroll
      for (int ni = 0; ni < 2; ++ni) {
        int row = n0w + ni * 16 + lrow;
        u32 off = ((u32)(row * 128 + ks * 64 + lk * 16)) ^ ((u32)((row & 7) << 4));
        bfr[ni] = Bb[off >> 4];
      }
#pragma unroll
      for (int mi = 0; mi < MI; ++mi)
#pragma unroll
        for (int ni = 0; ni < 2; ++ni)
          acc[mi][ni] = __builtin_amdgcn_mfma_f32_16x16x32_bf16(af[mi], bfr[ni], acc[mi][ni], 0, 0, 0);
    }
  }

  const float qsc = 0.088388347648318447f * 1.4426950408889634f;
#pragma unroll
  for (int ni = 0; ni < 2; ++ni) {
    int n = ntile * 64 + n0w + ni * 16 + lrow;
    float c0 = 0.f;
    if (MODE == 2 || MODE == 3) c0 = p0[n];
#pragma unroll
    for (int mi = 0; mi < MI; ++mi) {
#pragma unroll
      for (int r = 0; r < 4; ++r) {
        int grow = mbase + mtile * BM + m0w + mi * 16 + lk * 4 + r;
        float val = acc[mi][ni][r];
        if (MODE == 1) {
          if (blockIdx.z == 0) val *= qsc;
          int s = grow & 1023, b_ = grow >> 10;
          u16* ob = (u16*)Out + (size_t)blockIdx.z * 2097152;
          ob[(((size_t)(b_ * kH + (n >> 4))) * kS + s) * kDH + (n & 15)] = f2b(val);
        } else if (MODE == 2) {
          ((u16*)Out)[(size_t)grow * kDFF + n] = f2b(fmaxf(val + c0, 0.f));
        } else {
          ((float*)Out)[(size_t)grow * kE + n] = val + c0 + res[(size_t)grow * kE + n];
        }
      }
    }
  }
}

// =====================================================================
// MFMA attention v3: QK via 32x32x16 (all lanes, no zero-pad waste),
// exp2 (Q pre-scaled), cvt_pk_bf16 packing, PV via 16x16x32 (proven).
// =====================================================================
__global__ __launch_bounds__(512, 4) void attn_kernel(
    const u16* __restrict__ qb, const u16* __restrict__ kb,
    const u16* __restrict__ vb, const u16* __restrict__ rbT,
    float* __restrict__ o) {
  __shared__ u16 Vsh[16 * 1032];   // V^T [d][j], stride 1032
  __shared__ u16 Pt[8][1280];      // per-wave P [32 q][40 k]

  int tid = threadIdx.x;
  int quarter = blockIdx.x & 3;
  int h = (blockIdx.x >> 2) & 7;
  int bb = blockIdx.x >> 5;
  size_t base = (size_t)(bb * kH + h) * (kS * kDH);

  for (int j = tid; j < 1024; j += 512) {
    const uint4* src = (const uint4*)(vb + base + j * 16);
    uint4 a = src[0], b = src[1];
    u32 wv[8] = {a.x, a.y, a.z, a.w, b.x, b.y, b.z, b.w};
#pragma unroll
    for (int p = 0; p < 8; ++p) {
      Vsh[(2 * p) * 1032 + j]     = (u16)(wv[p] & 0xFFFFu);
      Vsh[(2 * p + 1) * 1032 + j] = (u16)(wv[p] >> 16);
    }
  }
  __syncthreads();

  int w = tid >> 6, l = tid & 63;
  int lr = l & 15, lg = l >> 4;      // PV-side coords
  int q32 = l & 31, hi = l >> 5;     // QK-side coords
  u16* P = Pt[w];
  int q0w = quarter * 256 + w * 32;
  int tbase = (q0w + 992) >> 4;
  const u16* rbh = rbT + (size_t)h * 126 * 512;

  // Q fragment (B-operand of 32x32x16): lane holds Q[q0w + q32][hi*8 .. +7]
  short8v qf = *(const short8v*)(qb + base + (size_t)(q0w + q32) * 16 + hi * 8);

  f32x4 acc_e[2], acc_rb[2];
  float lac = 0.f;
#pragma unroll
  for (int qt = 0; qt < 2; ++qt) {
    acc_e[qt] = (f32x4){0.f, 0.f, 0.f, 0.f};
    acc_rb[qt] = (f32x4){0.f, 0.f, 0.f, 0.f};
  }
  const f32x16 z16 = {0.f,0.f,0.f,0.f,0.f,0.f,0.f,0.f,0.f,0.f,0.f,0.f,0.f,0.f,0.f,0.f};

  for (int jb = 0; jb < 32; ++jb) {
    // K fragment (A-operand): lane holds K[jb*32 + q32][hi*8 .. +7]
    short8v kf = *(const short8v*)(kb + base + (size_t)(jb * 32 + q32) * 16 + hi * 8);
    // S^T: lane holds col q = q32, rows k = (reg&3) + 8*(reg>>2) + 4*hi
    f32x16 s = __builtin_amdgcn_mfma_f32_32x32x16_bf16(kf, qf, z16, 0, 0, 0);
    float ev[16];
#pragma unroll
    for (int r = 0; r < 16; ++r) {
      ev[r] = exp2f(s[r]);
      lac += ev[r];
    }
#pragma unroll
    for (int rq = 0; rq < 4; ++rq) {
      u32 p0, p1;
      asm("v_cvt_pk_bf16_f32 %0, %1, %2" : "=v"(p0) : "v"(ev[4 * rq]), "v"(ev[4 * rq + 1]));
      asm("v_cvt_pk_bf16_f32 %0, %1, %2" : "=v"(p1) : "v"(ev[4 * rq + 2]), "v"(ev[4 * rq + 3]));
      *(uint2*)(P + q32 * 40 + rq * 8 + hi * 4) = make_uint2(p0, p1);
    }
    short8v vf = *(const short8v*)(Vsh + lr * 1032 + jb * 32 + lg * 8);
#pragma unroll
    for (int qt = 0; qt < 2; ++qt) {
      short8v pf = *(const short8v*)(P + (qt * 16 + lr) * 40 + lg * 8);
      int t = tbase + qt - 2 * jb;
      short8v rf = *(const short8v*)(rbh + ((size_t)t * 64 + l) * 8);
      acc_e[qt]  = __builtin_amdgcn_mfma_f32_16x16x32_bf16(pf, vf, acc_e[qt], 0, 0, 0);
      acc_rb[qt] = __builtin_amdgcn_mfma_f32_16x16x32_bf16(rf, vf, acc_rb[qt], 0, 0, 0);
    }
  }

  lac += __shfl_xor(lac, 32);   // combine the two k-half partial sums per q
#pragma unroll
  for (int qt = 0; qt < 2; ++qt) {
#pragma unroll
    for (int r = 0; r < 4; ++r) {
      int qloc = qt * 16 + lg * 4 + r;
      float lsq = __shfl(lac, qloc);   // lanes 0..31 hold q=lane's sum
      int row = q0w + qloc;
      o[(size_t)(bb * kS + row) * kE + h * kDH + lr] = acc_e[qt][r] / lsq + acc_rb[qt][r];
    }
  }
}

// ---------------- LN(attn out) + residual + LN1 -> att (f32 + bf16) ----------------
__global__ __launch_bounds__(256) void ln_kernel(
    cfp o, cfp xsrc, cfp lag, cfp lab, cfp l1g, cfp l1b,
    float* __restrict__ att, u16* __restrict__ attb) {
  int row = blockIdx.x * 4 + (threadIdx.x >> 6);
  int lane = threadIdx.x & 63;
  float2 a = ((const float2*)(o + (size_t)row * kE))[lane];
  float sum = a.x + a.y;
  for (int off = 1; off < 64; off <<= 1) sum += __shfl_xor(sum, off);
  float mean = sum * (1.f / 128.f);
  float d0 = a.x - mean, d1 = a.y - mean;
  float ss = d0 * d0 + d1 * d1;
  for (int off = 1; off < 64; off <<= 1) ss += __shfl_xor(ss, off);
  float inv = 1.f / sqrtf(ss * (1.f / 128.f) + kEps);
  float t0 = d0 * inv * lag[2 * lane] + lab[2 * lane];
  float t1 = d1 * inv * lag[2 * lane + 1] + lab[2 * lane + 1];
  float2 xv = ((const float2*)(xsrc + (size_t)row * kE))[lane];
  t0 += xv.x; t1 += xv.y;
  float sum2 = t0 + t1;
  for (int off = 1; off < 64; off <<= 1) sum2 += __shfl_xor(sum2, off);
  float mean2 = sum2 * (1.f / 128.f);
  float e0 = t0 - mean2, e1 = t1 - mean2;
  float ss2 = e0 * e0 + e1 * e1;
  for (int off = 1; off < 64; off <<= 1) ss2 += __shfl_xor(ss2, off);
  float inv2 = 1.f / sqrtf(ss2 * (1.f / 128.f) + kEps);
  float r0 = e0 * inv2 * l1g[2 * lane] + l1b[2 * lane];
  float r1 = e1 * inv2 * l1g[2 * lane + 1] + l1b[2 * lane + 1];
  ((float2*)(att + (size_t)row * kE))[lane] = make_float2(r0, r1);
  ((u32*)attb)[(size_t)row * 64 + lane] = (u32)f2b(r0) | ((u32)f2b(r1) << 16);
}

// ---------------- LN2 + GAP ----------------
__global__ __launch_bounds__(256) void ln2gap_kernel(
    cfp yff, cfp l2g, cfp l2b, float* __restrict__ outacc) {
  __shared__ float red[128];
  int tid = threadIdx.x;
  if (tid < 128) red[tid] = 0.f;
  __syncthreads();
  int row = blockIdx.x * 4 + (tid >> 6);
  int lane = tid & 63;
  float2 a = ((const float2*)(yff + (size_t)row * kE))[lane];
  float sum = a.x + a.y;
  for (int off = 1; off < 64; off <<= 1) sum += __shfl_xor(sum, off);
  float mean = sum * (1.f / 128.f);
  float d0 = a.x - mean, d1 = a.y - mean;
  float ss = d0 * d0 + d1 * d1;
  for (int off = 1; off < 64; off <<= 1) ss += __shfl_xor(ss, off);
  float inv = 1.f / sqrtf(ss * (1.f / 128.f) + kEps);
  float r0 = d0 * inv * l2g[2 * lane] + l2b[2 * lane];
  float r1 = d1 * inv * l2g[2 * lane + 1] + l2b[2 * lane + 1];
  atomicAdd(&red[2 * lane], r0);
  atomicAdd(&red[2 * lane + 1], r1);
  __syncthreads();
  int bb = (blockIdx.x * 4) >> 10;
  if (tid < 128) atomicAdd(&outacc[bb * kE + tid], red[tid]);
}

// ---------------- finalize ----------------
__global__ void fin_kernel(cfp outacc, const int* __restrict__ flag, void* __restrict__ out) {
  int i = blockIdx.x * 256 + threadIdx.x;
  float v = outacc[i] * (1.f / 1024.f);
  if (*flag) ((float*)out)[i] = v;
  else       ((bf16*)out)[i] = __float2bfloat16(v);
}

extern "C" void kernel_launch(void* const* d_in, const int* in_sizes, int n_in,
                              void* d_out, int out_size, void* d_ws, size_t ws_size,
                              hipStream_t stream) {
  CvtArgs args;
  int cum = 0;
  for (int i = 0; i < n_in && i < 27; ++i) {
    args.p[i] = d_in[i];
    args.cum[i] = cum;
    cum += in_sizes[i];
  }
  args.cum[n_in] = cum;
  int total = cum;
  int totalPad = (total + 15) & ~15;

  float* ws = (float*)d_ws;
  int* flag    = (int*)ws;
  float* wsinf = ws + 16;
  float* xsrc  = wsinf + totalPad;               // 2,097,152 f32
  float* att   = xsrc + 2097152;                 // 2,097,152 f32
  float* qkv0  = att + 2097152;                  // 3,145,728 (q,k,v bf16)
  float* ext   = qkv0 + 3145728;                 // 1,048,576 (rbT; ff1b tail)
  float* o     = ext + 1048576;                  // 2,097,152 (later yff)
  float* outacc = o + 2097152;                   // 2,048
  u16* xpeb    = (u16*)(outacc + 2048);          // 2,097,152 u16
  u16* w2b     = xpeb + 2097152;                 // 262,144 u16

  u16* Abuf = (u16*)att;
  u16* qb = (u16*)qkv0;
  u16* kb = qb + 2097152;
  u16* vb = kb + 2097152;
  u16* rbT = (u16*)ext;
  u16* ff1b = (u16*)qkv0;
  u16* attb = xpeb;
  float* yff = o;

  const float* wf[27];
  for (int i = 0; i < n_in && i < 27; ++i) wf[i] = wsinf + args.cum[i];

  hipMemsetAsync(flag, 0, sizeof(int), stream);
  hipMemsetAsync(outacc, 0, 2048 * sizeof(float), stream);
  detect_kernel<<<(in_sizes[0] + 255) / 256, 256, 0, stream>>>(
      (const u16*)d_in[0], in_sizes[0], flag);
  convert_kernel<<<(total + 255) / 256, 256, 0, stream>>>(args, flag, wsinf, total);
  wcvt_kernel<<<128, 256, 0, stream>>>(wf[7], w2b);

  for (int hm = 0; hm < 2; ++hm) {
    convstage_kernel<<<8192, 256, 0, stream>>>(
        wf[0], wf[1], wf[2], wf[3], wf[4], wf[5], wf[6], Abuf, hm * 8192);
    convgemm_kernel<<<256, 256, 0, stream>>>(
        Abuf, w2b, wf[8], wf[9], wf[10], wf[11], wf[12], xsrc, xpeb, hm * 8192);
  }

  rbtab_kernel<<<dim3(126, 8), 64, 0, stream>>>(wf[16], rbT);

  gemm_kernel<3, 1, 128, 128><<<dim3(128, 2, 3), 256, 0, stream>>>(
      xpeb, wf[13], nullptr, wf[14], wf[15], nullptr, nullptr, nullptr,
      nullptr, nullptr, nullptr, nullptr, nullptr, qb, nullptr, nullptr, 0);

  attn_kernel<<<512, 512, 0, stream>>>(qb, kb, vb, rbT, o);
  ln_kernel<<<4096, 256, 0, stream>>>(o, xsrc, wf[17], wf[18], wf[19], wf[20], att, attb);

  gemm_kernel<3, 2, 128, 128><<<dim3(128, 8), 256, 0, stream>>>(
      attb, wf[21], wf[22], nullptr, nullptr, nullptr, nullptr, nullptr,
      nullptr, nullptr, nullptr, nullptr, nullptr, ff1b, nullptr, nullptr, 0);
  gemm_kernel<3, 3, 512, 128><<<dim3(128, 2), 256, 0, stream>>>(
      ff1b, wf[23], wf[24], nullptr, nullptr, nullptr, nullptr, nullptr,
      nullptr, nullptr, nullptr, nullptr, nullptr, yff, nullptr, att, 0);

  ln2gap_kernel<<<4096, 256, 0, stream>>>(yff, wf[25], wf[26], outacc);
  fin_kernel<<<8, 256, 0, stream>>>(outacc, flag, d_out);
}